// Round 6
// baseline (513.108 us; speedup 1.0000x reference)
//
#include <hip/hip_runtime.h>
#include <hip/hip_fp16.h>

// Simple GNN: h = X@W_in+b; 4x { agg = segmean(w*h[src], dst); h += lrelu(agg@W_l+b_l) }
// out = (h@W_out+b_out, h)
// Round 6: register-blocked layer GEMM (64-node M-tile, 8x4 per thread, 12 LDS ops /
//          128 FMA -> FMA-bound). fp16 h-mirror gather kept from round 5.

#define N_NODES 50000
#define N_EDGES 625000
#define IN_F 64
#define INT_F 128
#define OUT_F 32
#define DEPTH 4
#define NEG_SLOPE 0.01f

#define SCAN_BLOCKS 196  // 196*256 = 50176 >= N_NODES

// ---- in-degree (int) ----
__global__ void deg_kernel(const int2* __restrict__ ei, int* __restrict__ deg) {
    int i = blockIdx.x * blockDim.x + threadIdx.x;
    if (i < N_EDGES) atomicAdd(&deg[ei[i].y], 1);
}

// ---- scan stage 1 ----
__global__ void scan1_kernel(const int* __restrict__ deg, int* __restrict__ partial) {
    int node = blockIdx.x * 256 + threadIdx.x;
    int v = (node < N_NODES) ? deg[node] : 0;
    __shared__ int sd[256];
    sd[threadIdx.x] = v;
    __syncthreads();
    for (int off = 128; off > 0; off >>= 1) {
        if (threadIdx.x < off) sd[threadIdx.x] += sd[threadIdx.x + off];
        __syncthreads();
    }
    if (threadIdx.x == 0) partial[blockIdx.x] = sd[0];
}

// ---- scan stage 2 ----
__global__ void scan2_kernel(const int* __restrict__ partial, int* __restrict__ base,
                             int* __restrict__ row_ptr) {
    __shared__ int ps[256];
    int t = threadIdx.x;
    int v = (t < SCAN_BLOCKS) ? partial[t] : 0;
    ps[t] = v;
    __syncthreads();
    for (int off = 1; off < 256; off <<= 1) {
        int add = (t >= off) ? ps[t - off] : 0;
        __syncthreads();
        ps[t] += add;
        __syncthreads();
    }
    if (t < SCAN_BLOCKS) base[t] = ps[t] - v;
    if (t == SCAN_BLOCKS - 1) row_ptr[N_NODES] = ps[t];
}

// ---- scan stage 3 ----
__global__ void scan3_kernel(const int* __restrict__ deg, const int* __restrict__ base,
                             int* __restrict__ row_ptr, int* __restrict__ cursor) {
    int node = blockIdx.x * 256 + threadIdx.x;
    int t = threadIdx.x;
    int d = (node < N_NODES) ? deg[node] : 0;
    __shared__ int ps[256];
    ps[t] = d;
    __syncthreads();
    for (int off = 1; off < 256; off <<= 1) {
        int add = (t >= off) ? ps[t - off] : 0;
        __syncthreads();
        ps[t] += add;
        __syncthreads();
    }
    if (node < N_NODES) {
        int excl = base[blockIdx.x] + ps[t] - d;
        row_ptr[node] = excl;
        cursor[node] = excl;
    }
}

// ---- scatter edges into CSR slots ----
__global__ void build_csr_kernel(const int2* __restrict__ ei, const float* __restrict__ ew,
                                 int* __restrict__ cursor, int* __restrict__ csr_src,
                                 float* __restrict__ csr_w) {
    int e = blockIdx.x * blockDim.x + threadIdx.x;
    if (e >= N_EDGES) return;
    int2 sd = ei[e];
    int pos = atomicAdd(&cursor[sd.y], 1);
    csr_src[pos] = sd.x;
    csr_w[pos] = ew[e];
}

// ---- h = X @ W_in + b_in  (16 nodes per 256-thread block); also writes fp16 mirror ----
__global__ void gemm_in_kernel(const float* __restrict__ X, const float* __restrict__ W,
                               const float* __restrict__ b, float* __restrict__ h,
                               __half* __restrict__ h16) {
    __shared__ float xs[16][IN_F];
    const int base = blockIdx.x * 16;
    const int t = threadIdx.x;
    ((float4*)xs)[t] = ((const float4*)(X + (size_t)base * IN_F))[t];
    __syncthreads();
    const int f = t & (INT_F - 1);
    const int rg = t >> 7;
    float acc[8];
    const float bv = b[f];
#pragma unroll
    for (int j = 0; j < 8; ++j) acc[j] = bv;
#pragma unroll 4
    for (int k = 0; k < IN_F; ++k) {
        float w = W[k * INT_F + f];
#pragma unroll
        for (int j = 0; j < 8; ++j) acc[j] += xs[rg * 8 + j][k] * w;
    }
#pragma unroll
    for (int j = 0; j < 8; ++j) {
        size_t idx = (size_t)(base + rg * 8 + j) * INT_F + f;
        h[idx] = acc[j];
        h16[idx] = __float2half(acc[j]);
    }
}

// ---- agg16[n] = (1/deg) * sum w_e * h16[src_e]  (half-wave per node) ----
__global__ void gather_kernel(const int* __restrict__ row_ptr, const int* __restrict__ csr_src,
                              const float* __restrict__ csr_w, const uint2* __restrict__ h16v,
                              uint2* __restrict__ agg16v) {
    int gid = blockIdx.x * blockDim.x + threadIdx.x;
    int node = gid >> 5;
    int l = threadIdx.x & 31;
    if (node >= N_NODES) return;
    int s = row_ptr[node], e = row_ptr[node + 1];
    float4 acc = {0.f, 0.f, 0.f, 0.f};
    int i = s;
    for (; i + 1 < e; i += 2) {
        int s0 = csr_src[i], s1 = csr_src[i + 1];
        float w0 = csr_w[i], w1 = csr_w[i + 1];
        uint2 a = h16v[(size_t)s0 * 32 + l];
        uint2 c = h16v[(size_t)s1 * 32 + l];
        float2 a0 = __half22float2(*(const __half2*)&a.x);
        float2 a1 = __half22float2(*(const __half2*)&a.y);
        float2 c0 = __half22float2(*(const __half2*)&c.x);
        float2 c1 = __half22float2(*(const __half2*)&c.y);
        acc.x += w0 * a0.x + w1 * c0.x;
        acc.y += w0 * a0.y + w1 * c0.y;
        acc.z += w0 * a1.x + w1 * c1.x;
        acc.w += w0 * a1.y + w1 * c1.y;
    }
    if (i < e) {
        int s0 = csr_src[i];
        float w0 = csr_w[i];
        uint2 a = h16v[(size_t)s0 * 32 + l];
        float2 a0 = __half22float2(*(const __half2*)&a.x);
        float2 a1 = __half22float2(*(const __half2*)&a.y);
        acc.x += w0 * a0.x;
        acc.y += w0 * a0.y;
        acc.z += w0 * a1.x;
        acc.w += w0 * a1.y;
    }
    float inv = 1.0f / fmaxf((float)(e - s), 1.0f);
    __half2 o0 = __floats2half2_rn(acc.x * inv, acc.y * inv);
    __half2 o1 = __floats2half2_rn(acc.z * inv, acc.w * inv);
    uint2 o;
    o.x = *(const unsigned int*)&o0;
    o.y = *(const unsigned int*)&o1;
    agg16v[(size_t)node * 32 + l] = o;
}

// ---- register-blocked layer GEMM: 64 nodes/block, thread = 8 rows x 4 cols ----
// z = agg @ W + b ; h += lrelu(z); h16 = fp16(h)
__global__ __launch_bounds__(256) void layer_gemm_kernel(
    const uint4* __restrict__ agg16q, const float* __restrict__ W,
    const float* __restrict__ b, float* __restrict__ h, __half* __restrict__ h16) {
    __shared__ float as[64][INT_F];   // 32 KB A-tile (fp32)
    __shared__ float wsm[32][INT_F];  // 16 KB W k-chunk
    const int base = blockIdx.x * 64;
    const int t = threadIdx.x;

    // ---- stage A: 64 rows x 128 fp16 = 1024 uint4, convert to fp32 ----
#pragma unroll
    for (int it = 0; it < 4; ++it) {
        int idx = t + it * 256;          // 0..1023
        int row = idx >> 4;              // 16 uint4 per row
        int part = idx & 15;
        int grow = base + row;
        uint4 v;
        if (grow < N_NODES) v = agg16q[(size_t)grow * 16 + part];
        else v = make_uint4(0, 0, 0, 0);
        float2 f0 = __half22float2(*(const __half2*)&v.x);
        float2 f1 = __half22float2(*(const __half2*)&v.y);
        float2 f2 = __half22float2(*(const __half2*)&v.z);
        float2 f3 = __half22float2(*(const __half2*)&v.w);
        float4* dst = (float4*)&as[row][part << 3];
        dst[0] = make_float4(f0.x, f0.y, f1.x, f1.y);
        dst[1] = make_float4(f2.x, f2.y, f3.x, f3.y);
    }

    const int rg = t >> 5;       // 0..7 -> rows rg*8..rg*8+7
    const int cg = t & 31;       // cols 4*cg..4*cg+3
    float4 acc[8];
    const float4 biasv = ((const float4*)b)[cg];
#pragma unroll
    for (int r = 0; r < 8; ++r) acc[r] = make_float4(0.f, 0.f, 0.f, 0.f);

    const float4* Wg4 = (const float4*)W;           // [k][n] as float4: 32 per k-row
    const float4* as4 = (const float4*)as;
    float4* ws4 = (float4*)wsm;

    for (int kc = 0; kc < 4; ++kc) {  // 4 chunks of 32 k
        __syncthreads();              // protect wsm from previous iteration's readers
        // stage W chunk: 32x128 fp32 = 1024 float4
#pragma unroll
        for (int it = 0; it < 4; ++it) {
            int idx = t + it * 256;
            ws4[idx] = Wg4[kc * 1024 + idx];
        }
        __syncthreads();
#pragma unroll
        for (int kk = 0; kk < 8; ++kk) {  // 8 groups of 4 k
            float4 bv0 = ws4[(kk * 4 + 0) * 32 + cg];
            float4 bv1 = ws4[(kk * 4 + 1) * 32 + cg];
            float4 bv2 = ws4[(kk * 4 + 2) * 32 + cg];
            float4 bv3 = ws4[(kk * 4 + 3) * 32 + cg];
#pragma unroll
            for (int r = 0; r < 8; ++r) {
                float4 av = as4[(rg * 8 + r) * 32 + kc * 8 + kk];  // A[row][4k..4k+3]
                acc[r].x += av.x * bv0.x + av.y * bv1.x + av.z * bv2.x + av.w * bv3.x;
                acc[r].y += av.x * bv0.y + av.y * bv1.y + av.z * bv2.y + av.w * bv3.y;
                acc[r].z += av.x * bv0.z + av.y * bv1.z + av.z * bv2.z + av.w * bv3.z;
                acc[r].w += av.x * bv0.w + av.y * bv1.w + av.z * bv2.w + av.w * bv3.w;
            }
        }
    }

    // ---- epilogue: residual + leaky relu + fp16 mirror ----
    float4* h4 = (float4*)h;
    uint2* h16v = (uint2*)h16;
#pragma unroll
    for (int r = 0; r < 8; ++r) {
        int row = base + rg * 8 + r;
        if (row >= N_NODES) break;
        size_t idx = (size_t)row * 32 + cg;
        float4 z = acc[r];
        z.x += biasv.x; z.y += biasv.y; z.z += biasv.z; z.w += biasv.w;
        float4 hv = h4[idx];
        hv.x += (z.x >= 0.f) ? z.x : NEG_SLOPE * z.x;
        hv.y += (z.y >= 0.f) ? z.y : NEG_SLOPE * z.y;
        hv.z += (z.z >= 0.f) ? z.z : NEG_SLOPE * z.z;
        hv.w += (z.w >= 0.f) ? z.w : NEG_SLOPE * z.w;
        h4[idx] = hv;
        __half2 o0 = __floats2half2_rn(hv.x, hv.y);
        __half2 o1 = __floats2half2_rn(hv.z, hv.w);
        uint2 o;
        o.x = *(const unsigned int*)&o0;
        o.y = *(const unsigned int*)&o1;
        h16v[idx] = o;
    }
}

// ---- out = h @ W_out + b_out  (8 nodes per 256-thread block) ----
__global__ void gemm_out_kernel(const float* __restrict__ h, const float* __restrict__ W,
                                const float* __restrict__ b, float* __restrict__ out) {
    __shared__ float hr[8][INT_F];
    int base = blockIdx.x * 8;
    for (int t = threadIdx.x; t < 8 * INT_F; t += 256) {
        int n = t / INT_F, k = t % INT_F;
        int gn = base + n;
        hr[n][k] = (gn < N_NODES) ? h[(size_t)gn * INT_F + k] : 0.0f;
    }
    __syncthreads();
    int nl = threadIdx.x / OUT_F;
    int f = threadIdx.x % OUT_F;
    int node = base + nl;
    if (node >= N_NODES) return;
    float acc = b[f];
#pragma unroll 8
    for (int k = 0; k < INT_F; ++k) acc += hr[nl][k] * W[k * OUT_F + f];
    out[(size_t)node * OUT_F + f] = acc;
}

extern "C" void kernel_launch(void* const* d_in, const int* in_sizes, int n_in,
                              void* d_out, int out_size, void* d_ws, size_t ws_size,
                              hipStream_t stream) {
    const float* X        = (const float*)d_in[0];
    const int2*  ei       = (const int2*)d_in[1];
    const float* ew       = (const float*)d_in[2];
    const float* W_in     = (const float*)d_in[3];
    const float* b_in     = (const float*)d_in[4];
    const float* W_layers = (const float*)d_in[5];
    const float* b_layers = (const float*)d_in[6];
    const float* W_out    = (const float*)d_in[7];
    const float* b_out    = (const float*)d_in[8];

    float* out1 = (float*)d_out;
    float* h    = out1 + (size_t)N_NODES * OUT_F;  // second output doubles as h (fp32)

    // workspace layout (~31.5 MB)
    char* ws = (char*)d_ws;
    __half* h16   = (__half*)ws;  ws += (size_t)N_NODES * INT_F * 2;
    __half* agg16 = (__half*)ws;  ws += (size_t)N_NODES * INT_F * 2;
    float* csr_w   = (float*)ws;  ws += (size_t)N_EDGES * 4;
    int*   csr_src = (int*)ws;    ws += (size_t)N_EDGES * 4;
    int*   row_ptr = (int*)ws;    ws += (size_t)(N_NODES + 1) * 4;
    int*   cursor  = (int*)ws;    ws += (size_t)N_NODES * 4;
    int*   deg     = (int*)ws;    ws += (size_t)N_NODES * 4;
    int*   partial = (int*)ws;    ws += (size_t)SCAN_BLOCKS * 4;
    int*   bbase   = (int*)ws;    ws += (size_t)SCAN_BLOCKS * 4;

    // ---- build CSR ----
    hipMemsetAsync(deg, 0, (size_t)N_NODES * 4, stream);
    deg_kernel<<<(N_EDGES + 255) / 256, 256, 0, stream>>>(ei, deg);
    scan1_kernel<<<SCAN_BLOCKS, 256, 0, stream>>>(deg, partial);
    scan2_kernel<<<1, 256, 0, stream>>>(partial, bbase, row_ptr);
    scan3_kernel<<<SCAN_BLOCKS, 256, 0, stream>>>(deg, bbase, row_ptr, cursor);
    build_csr_kernel<<<(N_EDGES + 255) / 256, 256, 0, stream>>>(ei, ew, cursor, csr_src, csr_w);

    // ---- input projection ----
    gemm_in_kernel<<<N_NODES / 16, 256, 0, stream>>>(X, W_in, b_in, h, h16);

    // ---- layers ----
    for (int i = 0; i < DEPTH; ++i) {
        gather_kernel<<<(N_NODES * 32 + 255) / 256, 256, 0, stream>>>(
            row_ptr, csr_src, csr_w, (const uint2*)h16, (uint2*)agg16);
        layer_gemm_kernel<<<(N_NODES + 63) / 64, 256, 0, stream>>>(
            (const uint4*)agg16, W_layers + (size_t)i * INT_F * INT_F,
            b_layers + (size_t)i * INT_F, h, h16);
    }

    // ---- output projection ----
    gemm_out_kernel<<<(N_NODES + 7) / 8, 256, 0, stream>>>(h, W_out, b_out, out1);
}

// Round 8
// 386.675 us; speedup vs baseline: 1.3270x; 1.3270x over previous
//
#include <hip/hip_runtime.h>
#include <hip/hip_fp16.h>

// Simple GNN: h = X@W_in+b; 4x { agg = segmean(w*h[src], dst); h += lrelu(agg@W_l+b_l) }
// out = (h@W_out+b_out, h)
// Round 7b: MFMA layer GEMM (f32_16x16x32_f16, fp16 inputs / fp32 accumulate), zero LDS,
//           W pre-transposed to fp16 [n][k] once per call. Fix: _Float16 cast at call site.

#define N_NODES 50000
#define N_EDGES 625000
#define IN_F 64
#define INT_F 128
#define OUT_F 32
#define DEPTH 4
#define NEG_SLOPE 0.01f

#define SCAN_BLOCKS 196  // 196*256 = 50176 >= N_NODES

typedef _Float16 half8 __attribute__((ext_vector_type(8)));
typedef float floatx4 __attribute__((ext_vector_type(4)));

// ---- in-degree (int) ----
__global__ void deg_kernel(const int2* __restrict__ ei, int* __restrict__ deg) {
    int i = blockIdx.x * blockDim.x + threadIdx.x;
    if (i < N_EDGES) atomicAdd(&deg[ei[i].y], 1);
}

// ---- scan stage 1 ----
__global__ void scan1_kernel(const int* __restrict__ deg, int* __restrict__ partial) {
    int node = blockIdx.x * 256 + threadIdx.x;
    int v = (node < N_NODES) ? deg[node] : 0;
    __shared__ int sd[256];
    sd[threadIdx.x] = v;
    __syncthreads();
    for (int off = 128; off > 0; off >>= 1) {
        if (threadIdx.x < off) sd[threadIdx.x] += sd[threadIdx.x + off];
        __syncthreads();
    }
    if (threadIdx.x == 0) partial[blockIdx.x] = sd[0];
}

// ---- scan stage 2 ----
__global__ void scan2_kernel(const int* __restrict__ partial, int* __restrict__ base,
                             int* __restrict__ row_ptr) {
    __shared__ int ps[256];
    int t = threadIdx.x;
    int v = (t < SCAN_BLOCKS) ? partial[t] : 0;
    ps[t] = v;
    __syncthreads();
    for (int off = 1; off < 256; off <<= 1) {
        int add = (t >= off) ? ps[t - off] : 0;
        __syncthreads();
        ps[t] += add;
        __syncthreads();
    }
    if (t < SCAN_BLOCKS) base[t] = ps[t] - v;
    if (t == SCAN_BLOCKS - 1) row_ptr[N_NODES] = ps[t];
}

// ---- scan stage 3 ----
__global__ void scan3_kernel(const int* __restrict__ deg, const int* __restrict__ base,
                             int* __restrict__ row_ptr, int* __restrict__ cursor) {
    int node = blockIdx.x * 256 + threadIdx.x;
    int t = threadIdx.x;
    int d = (node < N_NODES) ? deg[node] : 0;
    __shared__ int ps[256];
    ps[t] = d;
    __syncthreads();
    for (int off = 1; off < 256; off <<= 1) {
        int add = (t >= off) ? ps[t - off] : 0;
        __syncthreads();
        ps[t] += add;
        __syncthreads();
    }
    if (node < N_NODES) {
        int excl = base[blockIdx.x] + ps[t] - d;
        row_ptr[node] = excl;
        cursor[node] = excl;
    }
}

// ---- scatter edges into CSR slots ----
__global__ void build_csr_kernel(const int2* __restrict__ ei, const float* __restrict__ ew,
                                 int* __restrict__ cursor, int* __restrict__ csr_src,
                                 float* __restrict__ csr_w) {
    int e = blockIdx.x * blockDim.x + threadIdx.x;
    if (e >= N_EDGES) return;
    int2 sd = ei[e];
    int pos = atomicAdd(&cursor[sd.y], 1);
    csr_src[pos] = sd.x;
    csr_w[pos] = ew[e];
}

// ---- WT16[l][n][k] = fp16(W_layers[l][k][n])  (4*128*128 = 65536 elements) ----
__global__ void prep_wt_kernel(const float* __restrict__ W_layers, _Float16* __restrict__ WT16) {
    int idx = blockIdx.x * 256 + threadIdx.x;
    int l = idx >> 14;
    int rem = idx & 16383;
    int n = rem >> 7;
    int k = rem & 127;
    WT16[idx] = (_Float16)W_layers[(size_t)l * 16384 + (size_t)k * 128 + n];
}

// ---- h = X @ W_in + b_in  (16 nodes per 256-thread block); also writes fp16 mirror ----
__global__ void gemm_in_kernel(const float* __restrict__ X, const float* __restrict__ W,
                               const float* __restrict__ b, float* __restrict__ h,
                               __half* __restrict__ h16) {
    __shared__ float xs[16][IN_F];
    const int base = blockIdx.x * 16;
    const int t = threadIdx.x;
    ((float4*)xs)[t] = ((const float4*)(X + (size_t)base * IN_F))[t];
    __syncthreads();
    const int f = t & (INT_F - 1);
    const int rg = t >> 7;
    float acc[8];
    const float bv = b[f];
#pragma unroll
    for (int j = 0; j < 8; ++j) acc[j] = bv;
#pragma unroll 4
    for (int k = 0; k < IN_F; ++k) {
        float w = W[k * INT_F + f];
#pragma unroll
        for (int j = 0; j < 8; ++j) acc[j] += xs[rg * 8 + j][k] * w;
    }
#pragma unroll
    for (int j = 0; j < 8; ++j) {
        size_t idx = (size_t)(base + rg * 8 + j) * INT_F + f;
        h[idx] = acc[j];
        h16[idx] = __float2half(acc[j]);
    }
}

// ---- agg16[n] = (1/deg) * sum w_e * h16[src_e]  (half-wave per node) ----
__global__ void gather_kernel(const int* __restrict__ row_ptr, const int* __restrict__ csr_src,
                              const float* __restrict__ csr_w, const uint2* __restrict__ h16v,
                              uint2* __restrict__ agg16v) {
    int gid = blockIdx.x * blockDim.x + threadIdx.x;
    int node = gid >> 5;
    int l = threadIdx.x & 31;
    if (node >= N_NODES) return;
    int s = row_ptr[node], e = row_ptr[node + 1];
    float4 acc = {0.f, 0.f, 0.f, 0.f};
    int i = s;
    for (; i + 1 < e; i += 2) {
        int s0 = csr_src[i], s1 = csr_src[i + 1];
        float w0 = csr_w[i], w1 = csr_w[i + 1];
        uint2 a = h16v[(size_t)s0 * 32 + l];
        uint2 c = h16v[(size_t)s1 * 32 + l];
        float2 a0 = __half22float2(*(const __half2*)&a.x);
        float2 a1 = __half22float2(*(const __half2*)&a.y);
        float2 c0 = __half22float2(*(const __half2*)&c.x);
        float2 c1 = __half22float2(*(const __half2*)&c.y);
        acc.x += w0 * a0.x + w1 * c0.x;
        acc.y += w0 * a0.y + w1 * c0.y;
        acc.z += w0 * a1.x + w1 * c1.x;
        acc.w += w0 * a1.y + w1 * c1.y;
    }
    if (i < e) {
        int s0 = csr_src[i];
        float w0 = csr_w[i];
        uint2 a = h16v[(size_t)s0 * 32 + l];
        float2 a0 = __half22float2(*(const __half2*)&a.x);
        float2 a1 = __half22float2(*(const __half2*)&a.y);
        acc.x += w0 * a0.x;
        acc.y += w0 * a0.y;
        acc.z += w0 * a1.x;
        acc.w += w0 * a1.y;
    }
    float inv = 1.0f / fmaxf((float)(e - s), 1.0f);
    __half2 o0 = __floats2half2_rn(acc.x * inv, acc.y * inv);
    __half2 o1 = __floats2half2_rn(acc.z * inv, acc.w * inv);
    uint2 o;
    o.x = *(const unsigned int*)&o0;
    o.y = *(const unsigned int*)&o1;
    agg16v[(size_t)node * 32 + l] = o;
}

// ---- MFMA layer GEMM: z = agg @ W + b ; h += lrelu(z); h16 = fp16(h) ----
// 256 threads = 4 waves; wave w owns rows [blk*64 + w*16, +16), all 128 cols.
// A frag: lane holds agg16[row0 + (lane&15)][ks*32 + (lane>>4)*8 .. +8]  (16B load)
// B frag: lane holds WT16[ct*16 + (lane&15)][ks*32 + (lane>>4)*8 .. +8]  (16B load)
// D frag: col = lane&15 (of 16-col tile), row = (lane>>4)*4 + reg   [m89-verified]
__global__ __launch_bounds__(256) void layer_mfma_kernel(
    const _Float16* __restrict__ agg16, const _Float16* __restrict__ WT16,
    const float* __restrict__ b, float* __restrict__ h, __half* __restrict__ h16) {
    const int t = threadIdx.x;
    const int wave = t >> 6;
    const int lane = t & 63;
    const int r = lane & 15;
    const int ksel = lane >> 4;  // 0..3

    const int row0 = blockIdx.x * 64 + wave * 16;
    int arow = row0 + r;
    int arow_c = (arow < N_NODES) ? arow : (N_NODES - 1);  // clamp loads, guard stores

    // A fragments for the 4 k-steps
    const _Float16* abase = agg16 + (size_t)arow_c * INT_F + ksel * 8;
    half8 a0 = *(const half8*)(abase + 0);
    half8 a1 = *(const half8*)(abase + 32);
    half8 a2 = *(const half8*)(abase + 64);
    half8 a3 = *(const half8*)(abase + 96);

    floatx4 acc[8];
#pragma unroll
    for (int ct = 0; ct < 8; ++ct) acc[ct] = (floatx4){0.f, 0.f, 0.f, 0.f};

#pragma unroll
    for (int ct = 0; ct < 8; ++ct) {
        const _Float16* wbase = WT16 + (size_t)(ct * 16 + r) * INT_F + ksel * 8;
        half8 b0 = *(const half8*)(wbase + 0);
        half8 b1 = *(const half8*)(wbase + 32);
        half8 b2 = *(const half8*)(wbase + 64);
        half8 b3 = *(const half8*)(wbase + 96);
        acc[ct] = __builtin_amdgcn_mfma_f32_16x16x32_f16(a0, b0, acc[ct], 0, 0, 0);
        acc[ct] = __builtin_amdgcn_mfma_f32_16x16x32_f16(a1, b1, acc[ct], 0, 0, 0);
        acc[ct] = __builtin_amdgcn_mfma_f32_16x16x32_f16(a2, b2, acc[ct], 0, 0, 0);
        acc[ct] = __builtin_amdgcn_mfma_f32_16x16x32_f16(a3, b3, acc[ct], 0, 0, 0);
    }

    // epilogue: D[row][col] with col = ct*16 + r, row = row0 + ksel*4 + reg
#pragma unroll
    for (int ct = 0; ct < 8; ++ct) {
        int col = ct * 16 + r;
        float bias = b[col];
#pragma unroll
        for (int reg = 0; reg < 4; ++reg) {
            int row = row0 + ksel * 4 + reg;
            if (row < N_NODES) {
                float z = acc[ct][reg] + bias;
                size_t idx = (size_t)row * INT_F + col;
                float nh = h[idx] + ((z >= 0.f) ? z : NEG_SLOPE * z);
                h[idx] = nh;
                h16[idx] = __float2half(nh);
            }
        }
    }
}

// ---- out = h @ W_out + b_out  (8 nodes per 256-thread block) ----
__global__ void gemm_out_kernel(const float* __restrict__ h, const float* __restrict__ W,
                                const float* __restrict__ b, float* __restrict__ out) {
    __shared__ float hr[8][INT_F];
    int base = blockIdx.x * 8;
    for (int t = threadIdx.x; t < 8 * INT_F; t += 256) {
        int n = t / INT_F, k = t % INT_F;
        int gn = base + n;
        hr[n][k] = (gn < N_NODES) ? h[(size_t)gn * INT_F + k] : 0.0f;
    }
    __syncthreads();
    int nl = threadIdx.x / OUT_F;
    int f = threadIdx.x % OUT_F;
    int node = base + nl;
    if (node >= N_NODES) return;
    float acc = b[f];
#pragma unroll 8
    for (int k = 0; k < INT_F; ++k) acc += hr[nl][k] * W[k * OUT_F + f];
    out[(size_t)node * OUT_F + f] = acc;
}

extern "C" void kernel_launch(void* const* d_in, const int* in_sizes, int n_in,
                              void* d_out, int out_size, void* d_ws, size_t ws_size,
                              hipStream_t stream) {
    const float* X        = (const float*)d_in[0];
    const int2*  ei       = (const int2*)d_in[1];
    const float* ew       = (const float*)d_in[2];
    const float* W_in     = (const float*)d_in[3];
    const float* b_in     = (const float*)d_in[4];
    const float* W_layers = (const float*)d_in[5];
    const float* b_layers = (const float*)d_in[6];
    const float* W_out    = (const float*)d_in[7];
    const float* b_out    = (const float*)d_in[8];

    float* out1 = (float*)d_out;
    float* h    = out1 + (size_t)N_NODES * OUT_F;  // second output doubles as h (fp32)

    // workspace layout (~31.7 MB); keep 16B alignment for fp16 vector loads
    char* ws = (char*)d_ws;
    __half*    h16   = (__half*)ws;    ws += (size_t)N_NODES * INT_F * 2;   // 12.8 MB
    __half*    agg16 = (__half*)ws;    ws += (size_t)N_NODES * INT_F * 2;   // 12.8 MB
    _Float16*  WT16  = (_Float16*)ws;  ws += (size_t)DEPTH * INT_F * INT_F * 2;  // 128 KB
    float* csr_w   = (float*)ws;  ws += (size_t)N_EDGES * 4;
    int*   csr_src = (int*)ws;    ws += (size_t)N_EDGES * 4;
    int*   row_ptr = (int*)ws;    ws += (size_t)(N_NODES + 1) * 4;
    int*   cursor  = (int*)ws;    ws += (size_t)N_NODES * 4;
    int*   deg     = (int*)ws;    ws += (size_t)N_NODES * 4;
    int*   partial = (int*)ws;    ws += (size_t)SCAN_BLOCKS * 4;
    int*   bbase   = (int*)ws;    ws += (size_t)SCAN_BLOCKS * 4;

    // ---- build CSR + transpose weights (once per call) ----
    (void)hipMemsetAsync(deg, 0, (size_t)N_NODES * 4, stream);
    deg_kernel<<<(N_EDGES + 255) / 256, 256, 0, stream>>>(ei, deg);
    scan1_kernel<<<SCAN_BLOCKS, 256, 0, stream>>>(deg, partial);
    scan2_kernel<<<1, 256, 0, stream>>>(partial, bbase, row_ptr);
    scan3_kernel<<<SCAN_BLOCKS, 256, 0, stream>>>(deg, bbase, row_ptr, cursor);
    build_csr_kernel<<<(N_EDGES + 255) / 256, 256, 0, stream>>>(ei, ew, cursor, csr_src, csr_w);
    prep_wt_kernel<<<(DEPTH * INT_F * INT_F) / 256, 256, 0, stream>>>(W_layers, WT16);

    // ---- input projection ----
    gemm_in_kernel<<<N_NODES / 16, 256, 0, stream>>>(X, W_in, b_in, h, h16);

    // ---- layers ----
    for (int i = 0; i < DEPTH; ++i) {
        gather_kernel<<<(N_NODES * 32 + 255) / 256, 256, 0, stream>>>(
            row_ptr, csr_src, csr_w, (const uint2*)h16, (uint2*)agg16);
        layer_mfma_kernel<<<(N_NODES + 63) / 64, 256, 0, stream>>>(
            (const _Float16*)agg16, WT16 + (size_t)i * INT_F * INT_F,
            b_layers + (size_t)i * INT_F, h, h16);
    }

    // ---- output projection ----
    gemm_out_kernel<<<(N_NODES + 7) / 8, 256, 0, stream>>>(h, W_out, b_out, out1);
}

// Round 9
// 339.873 us; speedup vs baseline: 1.5097x; 1.1377x over previous
//
#include <hip/hip_runtime.h>
#include <hip/hip_fp16.h>

// Simple GNN: h = X@W_in+b; 4x { agg = segmean(w*h[src], dst); h += lrelu(agg@W_l+b_l) }
// out = (h@W_out+b_out, h)
// Round 9: non-atomic CSR scatter (slot recorded in degree pass), paired int2 CSR
//          (one 8B scattered write/edge), quarter-wave uint4 gather. MFMA layer kept.

#define N_NODES 50000
#define N_EDGES 625000
#define IN_F 64
#define INT_F 128
#define OUT_F 32
#define DEPTH 4
#define NEG_SLOPE 0.01f

#define SCAN_BLOCKS 196  // 196*256 = 50176 >= N_NODES

typedef _Float16 half8 __attribute__((ext_vector_type(8)));
typedef float floatx4 __attribute__((ext_vector_type(4)));

// ---- in-degree + slot (slot = position of edge within its dst bucket) ----
__global__ void deg_slot_kernel(const int2* __restrict__ ei, int* __restrict__ deg,
                                int* __restrict__ slot) {
    int i = blockIdx.x * blockDim.x + threadIdx.x;
    if (i < N_EDGES) slot[i] = atomicAdd(&deg[ei[i].y], 1);
}

// ---- scan stage 1 ----
__global__ void scan1_kernel(const int* __restrict__ deg, int* __restrict__ partial) {
    int node = blockIdx.x * 256 + threadIdx.x;
    int v = (node < N_NODES) ? deg[node] : 0;
    __shared__ int sd[256];
    sd[threadIdx.x] = v;
    __syncthreads();
    for (int off = 128; off > 0; off >>= 1) {
        if (threadIdx.x < off) sd[threadIdx.x] += sd[threadIdx.x + off];
        __syncthreads();
    }
    if (threadIdx.x == 0) partial[blockIdx.x] = sd[0];
}

// ---- scan stage 2 ----
__global__ void scan2_kernel(const int* __restrict__ partial, int* __restrict__ base,
                             int* __restrict__ row_ptr) {
    __shared__ int ps[256];
    int t = threadIdx.x;
    int v = (t < SCAN_BLOCKS) ? partial[t] : 0;
    ps[t] = v;
    __syncthreads();
    for (int off = 1; off < 256; off <<= 1) {
        int add = (t >= off) ? ps[t - off] : 0;
        __syncthreads();
        ps[t] += add;
        __syncthreads();
    }
    if (t < SCAN_BLOCKS) base[t] = ps[t] - v;
    if (t == SCAN_BLOCKS - 1) row_ptr[N_NODES] = ps[t];
}

// ---- scan stage 3 ----
__global__ void scan3_kernel(const int* __restrict__ deg, const int* __restrict__ base,
                             int* __restrict__ row_ptr) {
    int node = blockIdx.x * 256 + threadIdx.x;
    int t = threadIdx.x;
    int d = (node < N_NODES) ? deg[node] : 0;
    __shared__ int ps[256];
    ps[t] = d;
    __syncthreads();
    for (int off = 1; off < 256; off <<= 1) {
        int add = (t >= off) ? ps[t - off] : 0;
        __syncthreads();
        ps[t] += add;
        __syncthreads();
    }
    if (node < N_NODES) row_ptr[node] = base[blockIdx.x] + ps[t] - d;
}

// ---- non-atomic scatter into paired CSR: csr[pos] = (src, weight_bits) ----
__global__ void build_csr_kernel(const int2* __restrict__ ei, const float* __restrict__ ew,
                                 const int* __restrict__ slot, const int* __restrict__ row_ptr,
                                 int2* __restrict__ csr) {
    int e = blockIdx.x * blockDim.x + threadIdx.x;
    if (e >= N_EDGES) return;
    int2 sd = ei[e];
    int pos = row_ptr[sd.y] + slot[e];
    csr[pos] = make_int2(sd.x, __float_as_int(ew[e]));
}

// ---- WT16[l][n][k] = fp16(W_layers[l][k][n]) ----
__global__ void prep_wt_kernel(const float* __restrict__ W_layers, _Float16* __restrict__ WT16) {
    int idx = blockIdx.x * 256 + threadIdx.x;
    int l = idx >> 14;
    int rem = idx & 16383;
    int n = rem >> 7;
    int k = rem & 127;
    WT16[idx] = (_Float16)W_layers[(size_t)l * 16384 + (size_t)k * 128 + n];
}

// ---- h = X @ W_in + b_in  (16 nodes per 256-thread block); also writes fp16 mirror ----
__global__ void gemm_in_kernel(const float* __restrict__ X, const float* __restrict__ W,
                               const float* __restrict__ b, float* __restrict__ h,
                               __half* __restrict__ h16) {
    __shared__ float xs[16][IN_F];
    const int base = blockIdx.x * 16;
    const int t = threadIdx.x;
    ((float4*)xs)[t] = ((const float4*)(X + (size_t)base * IN_F))[t];
    __syncthreads();
    const int f = t & (INT_F - 1);
    const int rg = t >> 7;
    float acc[8];
    const float bv = b[f];
#pragma unroll
    for (int j = 0; j < 8; ++j) acc[j] = bv;
#pragma unroll 4
    for (int k = 0; k < IN_F; ++k) {
        float w = W[k * INT_F + f];
#pragma unroll
        for (int j = 0; j < 8; ++j) acc[j] += xs[rg * 8 + j][k] * w;
    }
#pragma unroll
    for (int j = 0; j < 8; ++j) {
        size_t idx = (size_t)(base + rg * 8 + j) * INT_F + f;
        h[idx] = acc[j];
        h16[idx] = __float2half(acc[j]);
    }
}

// ---- agg16[n] = (1/deg) * sum w_e * h16[src_e]  (quarter-wave per node, uint4/lane) ----
__global__ void gather_kernel(const int* __restrict__ row_ptr, const int2* __restrict__ csr,
                              const uint4* __restrict__ h16q, uint4* __restrict__ agg16q) {
    int gid = blockIdx.x * blockDim.x + threadIdx.x;
    int node = gid >> 4;  // quarter-wave per node
    int l = threadIdx.x & 15;
    if (node >= N_NODES) return;
    int s = row_ptr[node], e = row_ptr[node + 1];
    float acc[8] = {0.f, 0.f, 0.f, 0.f, 0.f, 0.f, 0.f, 0.f};
    int i = s;
    for (; i + 1 < e; i += 2) {
        int2 e0 = csr[i], e1 = csr[i + 1];  // broadcast 8B loads
        float w0 = __int_as_float(e0.y), w1 = __int_as_float(e1.y);
        uint4 a = h16q[(size_t)e0.x * 16 + l];  // 256B per row per quarter-wave
        uint4 c = h16q[(size_t)e1.x * 16 + l];
#pragma unroll
        for (int q = 0; q < 4; ++q) {
            float2 fa = __half22float2(*(const __half2*)(&(&a.x)[q]));
            float2 fc = __half22float2(*(const __half2*)(&(&c.x)[q]));
            acc[2 * q + 0] += w0 * fa.x + w1 * fc.x;
            acc[2 * q + 1] += w0 * fa.y + w1 * fc.y;
        }
    }
    if (i < e) {
        int2 e0 = csr[i];
        float w0 = __int_as_float(e0.y);
        uint4 a = h16q[(size_t)e0.x * 16 + l];
#pragma unroll
        for (int q = 0; q < 4; ++q) {
            float2 fa = __half22float2(*(const __half2*)(&(&a.x)[q]));
            acc[2 * q + 0] += w0 * fa.x;
            acc[2 * q + 1] += w0 * fa.y;
        }
    }
    float inv = 1.0f / fmaxf((float)(e - s), 1.0f);
    uint4 o;
    unsigned int* op = &o.x;
#pragma unroll
    for (int q = 0; q < 4; ++q) {
        __half2 hv = __floats2half2_rn(acc[2 * q] * inv, acc[2 * q + 1] * inv);
        op[q] = *(const unsigned int*)&hv;
    }
    agg16q[(size_t)node * 16 + l] = o;
}

// ---- MFMA layer GEMM: z = agg @ W + b ; h += lrelu(z); h16 = fp16(h) ----
// 256 threads = 4 waves; wave w owns rows [blk*64 + w*16, +16), all 128 cols.
__global__ __launch_bounds__(256) void layer_mfma_kernel(
    const _Float16* __restrict__ agg16, const _Float16* __restrict__ WT16,
    const float* __restrict__ b, float* __restrict__ h, __half* __restrict__ h16) {
    const int t = threadIdx.x;
    const int wave = t >> 6;
    const int lane = t & 63;
    const int r = lane & 15;
    const int ksel = lane >> 4;  // 0..3

    const int row0 = blockIdx.x * 64 + wave * 16;
    int arow = row0 + r;
    int arow_c = (arow < N_NODES) ? arow : (N_NODES - 1);  // clamp loads, guard stores

    const _Float16* abase = agg16 + (size_t)arow_c * INT_F + ksel * 8;
    half8 a0 = *(const half8*)(abase + 0);
    half8 a1 = *(const half8*)(abase + 32);
    half8 a2 = *(const half8*)(abase + 64);
    half8 a3 = *(const half8*)(abase + 96);

    floatx4 acc[8];
#pragma unroll
    for (int ct = 0; ct < 8; ++ct) acc[ct] = (floatx4){0.f, 0.f, 0.f, 0.f};

#pragma unroll
    for (int ct = 0; ct < 8; ++ct) {
        const _Float16* wbase = WT16 + (size_t)(ct * 16 + r) * INT_F + ksel * 8;
        half8 b0 = *(const half8*)(wbase + 0);
        half8 b1 = *(const half8*)(wbase + 32);
        half8 b2 = *(const half8*)(wbase + 64);
        half8 b3 = *(const half8*)(wbase + 96);
        acc[ct] = __builtin_amdgcn_mfma_f32_16x16x32_f16(a0, b0, acc[ct], 0, 0, 0);
        acc[ct] = __builtin_amdgcn_mfma_f32_16x16x32_f16(a1, b1, acc[ct], 0, 0, 0);
        acc[ct] = __builtin_amdgcn_mfma_f32_16x16x32_f16(a2, b2, acc[ct], 0, 0, 0);
        acc[ct] = __builtin_amdgcn_mfma_f32_16x16x32_f16(a3, b3, acc[ct], 0, 0, 0);
    }

#pragma unroll
    for (int ct = 0; ct < 8; ++ct) {
        int col = ct * 16 + r;
        float bias = b[col];
#pragma unroll
        for (int reg = 0; reg < 4; ++reg) {
            int row = row0 + ksel * 4 + reg;
            if (row < N_NODES) {
                float z = acc[ct][reg] + bias;
                size_t idx = (size_t)row * INT_F + col;
                float nh = h[idx] + ((z >= 0.f) ? z : NEG_SLOPE * z);
                h[idx] = nh;
                h16[idx] = __float2half(nh);
            }
        }
    }
}

// ---- out = h @ W_out + b_out  (8 nodes per 256-thread block) ----
__global__ void gemm_out_kernel(const float* __restrict__ h, const float* __restrict__ W,
                                const float* __restrict__ b, float* __restrict__ out) {
    __shared__ float hr[8][INT_F];
    int base = blockIdx.x * 8;
    for (int t = threadIdx.x; t < 8 * INT_F; t += 256) {
        int n = t / INT_F, k = t % INT_F;
        int gn = base + n;
        hr[n][k] = (gn < N_NODES) ? h[(size_t)gn * INT_F + k] : 0.0f;
    }
    __syncthreads();
    int nl = threadIdx.x / OUT_F;
    int f = threadIdx.x % OUT_F;
    int node = base + nl;
    if (node >= N_NODES) return;
    float acc = b[f];
#pragma unroll 8
    for (int k = 0; k < INT_F; ++k) acc += hr[nl][k] * W[k * OUT_F + f];
    out[(size_t)node * OUT_F + f] = acc;
}

extern "C" void kernel_launch(void* const* d_in, const int* in_sizes, int n_in,
                              void* d_out, int out_size, void* d_ws, size_t ws_size,
                              hipStream_t stream) {
    const float* X        = (const float*)d_in[0];
    const int2*  ei       = (const int2*)d_in[1];
    const float* ew       = (const float*)d_in[2];
    const float* W_in     = (const float*)d_in[3];
    const float* b_in     = (const float*)d_in[4];
    const float* W_layers = (const float*)d_in[5];
    const float* b_layers = (const float*)d_in[6];
    const float* W_out    = (const float*)d_in[7];
    const float* b_out    = (const float*)d_in[8];

    float* out1 = (float*)d_out;
    float* h    = out1 + (size_t)N_NODES * OUT_F;  // second output doubles as h (fp32)

    // workspace layout (~34 MB); keep 16B alignment for fp16 vector loads
    char* ws = (char*)d_ws;
    __half*    h16   = (__half*)ws;    ws += (size_t)N_NODES * INT_F * 2;        // 12.8 MB
    __half*    agg16 = (__half*)ws;    ws += (size_t)N_NODES * INT_F * 2;        // 12.8 MB
    _Float16*  WT16  = (_Float16*)ws;  ws += (size_t)DEPTH * INT_F * INT_F * 2;  // 128 KB
    int2*  csr     = (int2*)ws;   ws += (size_t)N_EDGES * 8;    // 5 MB (src, w) pairs
    int*   slot    = (int*)ws;    ws += (size_t)N_EDGES * 4;    // 2.5 MB
    int*   row_ptr = (int*)ws;    ws += (size_t)(N_NODES + 1) * 4;
    int*   deg     = (int*)ws;    ws += (size_t)N_NODES * 4;
    int*   partial = (int*)ws;    ws += (size_t)SCAN_BLOCKS * 4;
    int*   bbase   = (int*)ws;    ws += (size_t)SCAN_BLOCKS * 4;

    // ---- build CSR + transpose weights (once per call) ----
    (void)hipMemsetAsync(deg, 0, (size_t)N_NODES * 4, stream);
    deg_slot_kernel<<<(N_EDGES + 255) / 256, 256, 0, stream>>>(ei, deg, slot);
    scan1_kernel<<<SCAN_BLOCKS, 256, 0, stream>>>(deg, partial);
    scan2_kernel<<<1, 256, 0, stream>>>(partial, bbase, row_ptr);
    scan3_kernel<<<SCAN_BLOCKS, 256, 0, stream>>>(deg, bbase, row_ptr);
    build_csr_kernel<<<(N_EDGES + 255) / 256, 256, 0, stream>>>(ei, ew, slot, row_ptr, csr);
    prep_wt_kernel<<<(DEPTH * INT_F * INT_F) / 256, 256, 0, stream>>>(W_layers, WT16);

    // ---- input projection ----
    gemm_in_kernel<<<N_NODES / 16, 256, 0, stream>>>(X, W_in, b_in, h, h16);

    // ---- layers ----
    for (int i = 0; i < DEPTH; ++i) {
        gather_kernel<<<(N_NODES * 16 + 255) / 256, 256, 0, stream>>>(
            row_ptr, csr, (const uint4*)h16, (uint4*)agg16);
        layer_mfma_kernel<<<(N_NODES + 63) / 64, 256, 0, stream>>>(
            (const _Float16*)agg16, WT16 + (size_t)i * INT_F * INT_F,
            b_layers + (size_t)i * INT_F, h, h16);
    }

    // ---- output projection ----
    gemm_out_kernel<<<(N_NODES + 7) / 8, 256, 0, stream>>>(h, W_out, b_out, out1);
}

// Round 10
// 326.840 us; speedup vs baseline: 1.5699x; 1.0399x over previous
//
#include <hip/hip_runtime.h>
#include <hip/hip_fp16.h>

// Simple GNN: h = X@W_in+b; 4x { agg = segmean(w*h[src], dst); h += lrelu(agg@W_l+b_l) }
// out = (h@W_out+b_out, h)
// Round 10: wave-level fused gather+MFMA layer (1 wave = 16 nodes, 4 lanes/node gather,
//           padded-LDS A-tile, same-wave MFMA). h carried as fp16 only (ping-pong);
//           last layer writes the fp32 h output. agg16 buffer eliminated.

#define N_NODES 50000
#define N_EDGES 625000
#define IN_F 64
#define INT_F 128
#define OUT_F 32
#define DEPTH 4
#define NEG_SLOPE 0.01f

#define SCAN_BLOCKS 196  // 196*256 = 50176 >= N_NODES

typedef _Float16 half8 __attribute__((ext_vector_type(8)));
typedef float floatx4 __attribute__((ext_vector_type(4)));

// ---- in-degree + slot (slot = position of edge within its dst bucket) ----
__global__ void deg_slot_kernel(const int2* __restrict__ ei, int* __restrict__ deg,
                                int* __restrict__ slot) {
    int i = blockIdx.x * blockDim.x + threadIdx.x;
    if (i < N_EDGES) slot[i] = atomicAdd(&deg[ei[i].y], 1);
}

// ---- scan stage 1 ----
__global__ void scan1_kernel(const int* __restrict__ deg, int* __restrict__ partial) {
    int node = blockIdx.x * 256 + threadIdx.x;
    int v = (node < N_NODES) ? deg[node] : 0;
    __shared__ int sd[256];
    sd[threadIdx.x] = v;
    __syncthreads();
    for (int off = 128; off > 0; off >>= 1) {
        if (threadIdx.x < off) sd[threadIdx.x] += sd[threadIdx.x + off];
        __syncthreads();
    }
    if (threadIdx.x == 0) partial[blockIdx.x] = sd[0];
}

// ---- scan stage 2 ----
__global__ void scan2_kernel(const int* __restrict__ partial, int* __restrict__ base,
                             int* __restrict__ row_ptr) {
    __shared__ int ps[256];
    int t = threadIdx.x;
    int v = (t < SCAN_BLOCKS) ? partial[t] : 0;
    ps[t] = v;
    __syncthreads();
    for (int off = 1; off < 256; off <<= 1) {
        int add = (t >= off) ? ps[t - off] : 0;
        __syncthreads();
        ps[t] += add;
        __syncthreads();
    }
    if (t < SCAN_BLOCKS) base[t] = ps[t] - v;
    if (t == SCAN_BLOCKS - 1) row_ptr[N_NODES] = ps[t];
}

// ---- scan stage 3 ----
__global__ void scan3_kernel(const int* __restrict__ deg, const int* __restrict__ base,
                             int* __restrict__ row_ptr) {
    int node = blockIdx.x * 256 + threadIdx.x;
    int t = threadIdx.x;
    int d = (node < N_NODES) ? deg[node] : 0;
    __shared__ int ps[256];
    ps[t] = d;
    __syncthreads();
    for (int off = 1; off < 256; off <<= 1) {
        int add = (t >= off) ? ps[t - off] : 0;
        __syncthreads();
        ps[t] += add;
        __syncthreads();
    }
    if (node < N_NODES) row_ptr[node] = base[blockIdx.x] + ps[t] - d;
}

// ---- non-atomic scatter into paired CSR: csr[pos] = (src, weight_bits) ----
__global__ void build_csr_kernel(const int2* __restrict__ ei, const float* __restrict__ ew,
                                 const int* __restrict__ slot, const int* __restrict__ row_ptr,
                                 int2* __restrict__ csr) {
    int e = blockIdx.x * blockDim.x + threadIdx.x;
    if (e >= N_EDGES) return;
    int2 sd = ei[e];
    int pos = row_ptr[sd.y] + slot[e];
    csr[pos] = make_int2(sd.x, __float_as_int(ew[e]));
}

// ---- WT16[l][n][k] = fp16(W_layers[l][k][n]) ----
__global__ void prep_wt_kernel(const float* __restrict__ W_layers, _Float16* __restrict__ WT16) {
    int idx = blockIdx.x * 256 + threadIdx.x;
    int l = idx >> 14;
    int rem = idx & 16383;
    int n = rem >> 7;
    int k = rem & 127;
    WT16[idx] = (_Float16)W_layers[(size_t)l * 16384 + (size_t)k * 128 + n];
}

// ---- h16 = fp16(X @ W_in + b_in)  (16 nodes per 256-thread block) ----
__global__ void gemm_in_kernel(const float* __restrict__ X, const float* __restrict__ W,
                               const float* __restrict__ b, __half* __restrict__ h16) {
    __shared__ float xs[16][IN_F];
    const int base = blockIdx.x * 16;
    const int t = threadIdx.x;
    ((float4*)xs)[t] = ((const float4*)(X + (size_t)base * IN_F))[t];
    __syncthreads();
    const int f = t & (INT_F - 1);
    const int rg = t >> 7;
    float acc[8];
    const float bv = b[f];
#pragma unroll
    for (int j = 0; j < 8; ++j) acc[j] = bv;
#pragma unroll 4
    for (int k = 0; k < IN_F; ++k) {
        float w = W[k * INT_F + f];
#pragma unroll
        for (int j = 0; j < 8; ++j) acc[j] += xs[rg * 8 + j][k] * w;
    }
#pragma unroll
    for (int j = 0; j < 8; ++j)
        h16[(size_t)(base + rg * 8 + j) * INT_F + f] = __float2half(acc[j]);
}

// ---- fused layer: 1 wave = 16 nodes. gather(4 lanes/node) -> LDS A-tile -> MFMA ----
// h16_out[n] = fp16( fp32(h16_in[n]) + lrelu( segmean_n @ W + b ) ); optionally fp32 out.
__global__ __launch_bounds__(64) void fused_layer_kernel(
    const int* __restrict__ row_ptr, const int2* __restrict__ csr,
    const __half* h16_in, const _Float16* __restrict__ WT16,
    const float* __restrict__ b, __half* __restrict__ h16_out,
    float* __restrict__ h_fp32_out /* null except last layer */) {
    __shared__ _Float16 as[16 * 136];  // 16 rows x 272B (128 halves + 8 pad) -> conflict-free
    const int lane = threadIdx.x;      // 0..63
    const int row0 = blockIdx.x * 16;  // 3125 * 16 == 50000, no bounds checks

    // ---- phase 1: gather. 4 lanes per node; lane covers 32 features (64B). ----
    const int nl = lane >> 2;   // local node 0..15
    const int sl = lane & 3;    // feature quarter
    const int node = row0 + nl;
    const uint4* h16q = (const uint4*)h16_in;

    const int s = row_ptr[node], e = row_ptr[node + 1];
    float acc[32];
#pragma unroll
    for (int j = 0; j < 32; ++j) acc[j] = 0.f;

    int i = s;
    for (; i + 1 < e; i += 2) {
        int2 e0 = csr[i], e1 = csr[i + 1];
        float w0 = __int_as_float(e0.y), w1 = __int_as_float(e1.y);
        const uint4* r0 = h16q + (size_t)e0.x * 16 + sl * 4;
        const uint4* r1 = h16q + (size_t)e1.x * 16 + sl * 4;
        uint4 a0 = r0[0], a1 = r0[1], a2 = r0[2], a3 = r0[3];
        uint4 c0 = r1[0], c1 = r1[1], c2 = r1[2], c3 = r1[3];
        const uint4 av[4] = {a0, a1, a2, a3};
        const uint4 cv[4] = {c0, c1, c2, c3};
#pragma unroll
        for (int u = 0; u < 4; ++u) {
            const __half2* ha = (const __half2*)&av[u];
            const __half2* hc = (const __half2*)&cv[u];
#pragma unroll
            for (int q = 0; q < 4; ++q) {
                float2 fa = __half22float2(ha[q]);
                float2 fc = __half22float2(hc[q]);
                acc[u * 8 + 2 * q + 0] += w0 * fa.x + w1 * fc.x;
                acc[u * 8 + 2 * q + 1] += w0 * fa.y + w1 * fc.y;
            }
        }
    }
    if (i < e) {
        int2 e0 = csr[i];
        float w0 = __int_as_float(e0.y);
        const uint4* r0 = h16q + (size_t)e0.x * 16 + sl * 4;
#pragma unroll
        for (int u = 0; u < 4; ++u) {
            uint4 a = r0[u];
            const __half2* ha = (const __half2*)&a;
#pragma unroll
            for (int q = 0; q < 4; ++q) {
                float2 fa = __half22float2(ha[q]);
                acc[u * 8 + 2 * q + 0] += w0 * fa.x;
                acc[u * 8 + 2 * q + 1] += w0 * fa.y;
            }
        }
    }
    const float inv = 1.0f / fmaxf((float)(e - s), 1.0f);

    // stage to LDS: row nl, halves [sl*32, sl*32+32), row stride 136 halves
#pragma unroll
    for (int u = 0; u < 4; ++u) {
        uint4 o;
        unsigned int* op = &o.x;
#pragma unroll
        for (int q = 0; q < 4; ++q) {
            __half2 hv = __floats2half2_rn(acc[u * 8 + 2 * q] * inv, acc[u * 8 + 2 * q + 1] * inv);
            op[q] = *(const unsigned int*)&hv;
        }
        *(uint4*)(as + nl * 136 + sl * 32 + u * 8) = o;
    }
    __syncthreads();  // single wave: compiles to a cheap lgkmcnt drain + barrier

    // ---- phase 2: MFMA. wave owns rows row0..row0+15, all 128 cols. ----
    const int r = lane & 15;
    const int ksel = lane >> 4;  // 0..3

    half8 afr[4];
#pragma unroll
    for (int ks = 0; ks < 4; ++ks)
        afr[ks] = *(const half8*)(as + r * 136 + ks * 32 + ksel * 8);

    floatx4 accd[8];
#pragma unroll
    for (int ct = 0; ct < 8; ++ct) accd[ct] = (floatx4){0.f, 0.f, 0.f, 0.f};

#pragma unroll
    for (int ct = 0; ct < 8; ++ct) {
        const _Float16* wbase = WT16 + (size_t)(ct * 16 + r) * INT_F + ksel * 8;
        half8 b0 = *(const half8*)(wbase + 0);
        half8 b1 = *(const half8*)(wbase + 32);
        half8 b2 = *(const half8*)(wbase + 64);
        half8 b3 = *(const half8*)(wbase + 96);
        accd[ct] = __builtin_amdgcn_mfma_f32_16x16x32_f16(afr[0], b0, accd[ct], 0, 0, 0);
        accd[ct] = __builtin_amdgcn_mfma_f32_16x16x32_f16(afr[1], b1, accd[ct], 0, 0, 0);
        accd[ct] = __builtin_amdgcn_mfma_f32_16x16x32_f16(afr[2], b2, accd[ct], 0, 0, 0);
        accd[ct] = __builtin_amdgcn_mfma_f32_16x16x32_f16(afr[3], b3, accd[ct], 0, 0, 0);
    }

    // ---- phase 3: epilogue. D[row][col]: col = ct*16 + r, row = row0 + ksel*4 + reg ----
#pragma unroll
    for (int ct = 0; ct < 8; ++ct) {
        int col = ct * 16 + r;
        float bias = b[col];
#pragma unroll
        for (int reg = 0; reg < 4; ++reg) {
            int row = row0 + ksel * 4 + reg;
            size_t idx = (size_t)row * INT_F + col;
            float z = accd[ct][reg] + bias;
            float nh = __half2float(h16_in[idx]) + ((z >= 0.f) ? z : NEG_SLOPE * z);
            h16_out[idx] = __float2half(nh);
            if (h_fp32_out) h_fp32_out[idx] = nh;
        }
    }
}

// ---- out = h16 @ W_out + b_out  (8 nodes per 256-thread block) ----
__global__ void gemm_out_kernel(const __half* __restrict__ h16, const float* __restrict__ W,
                                const float* __restrict__ b, float* __restrict__ out) {
    __shared__ float hr[8][INT_F];
    const int base = blockIdx.x * 8;  // 6250 * 8 == 50000, exact
    const int t = threadIdx.x;
    if (t < 128) {
        int n = t >> 4, part = t & 15;
        uint4 v = ((const uint4*)h16)[(size_t)(base + n) * 16 + part];
        const __half2* hp = (const __half2*)&v;
        float* dst = &hr[n][part * 8];
#pragma unroll
        for (int q = 0; q < 4; ++q) {
            float2 f = __half22float2(hp[q]);
            dst[2 * q] = f.x;
            dst[2 * q + 1] = f.y;
        }
    }
    __syncthreads();
    int nl = t >> 5;          // 0..7
    int f = t & 31;           // 0..31
    int node = base + nl;
    float acc = b[f];
#pragma unroll 8
    for (int k = 0; k < INT_F; ++k) acc += hr[nl][k] * W[k * OUT_F + f];
    out[(size_t)node * OUT_F + f] = acc;
}

extern "C" void kernel_launch(void* const* d_in, const int* in_sizes, int n_in,
                              void* d_out, int out_size, void* d_ws, size_t ws_size,
                              hipStream_t stream) {
    const float* X        = (const float*)d_in[0];
    const int2*  ei       = (const int2*)d_in[1];
    const float* ew       = (const float*)d_in[2];
    const float* W_in     = (const float*)d_in[3];
    const float* b_in     = (const float*)d_in[4];
    const float* W_layers = (const float*)d_in[5];
    const float* b_layers = (const float*)d_in[6];
    const float* W_out    = (const float*)d_in[7];
    const float* b_out    = (const float*)d_in[8];

    float* out1 = (float*)d_out;
    float* hf32 = out1 + (size_t)N_NODES * OUT_F;  // fp32 h output (written by last layer)

    // workspace layout (~34 MB); 16B alignment maintained
    char* ws = (char*)d_ws;
    __half*   h16A  = (__half*)ws;    ws += (size_t)N_NODES * INT_F * 2;        // 12.8 MB
    __half*   h16B  = (__half*)ws;    ws += (size_t)N_NODES * INT_F * 2;        // 12.8 MB
    _Float16* WT16  = (_Float16*)ws;  ws += (size_t)DEPTH * INT_F * INT_F * 2;  // 128 KB
    int2* csr     = (int2*)ws;  ws += (size_t)N_EDGES * 8;                      // 5 MB
    int*  slot    = (int*)ws;   ws += (size_t)N_EDGES * 4;                      // 2.5 MB
    int*  row_ptr = (int*)ws;   ws += (size_t)(N_NODES + 1) * 4;
    int*  deg     = (int*)ws;   ws += (size_t)N_NODES * 4;
    int*  partial = (int*)ws;   ws += (size_t)SCAN_BLOCKS * 4;
    int*  bbase   = (int*)ws;   ws += (size_t)SCAN_BLOCKS * 4;

    // ---- build CSR + transpose weights (once per call) ----
    (void)hipMemsetAsync(deg, 0, (size_t)N_NODES * 4, stream);
    deg_slot_kernel<<<(N_EDGES + 255) / 256, 256, 0, stream>>>(ei, deg, slot);
    scan1_kernel<<<SCAN_BLOCKS, 256, 0, stream>>>(deg, partial);
    scan2_kernel<<<1, 256, 0, stream>>>(partial, bbase, row_ptr);
    scan3_kernel<<<SCAN_BLOCKS, 256, 0, stream>>>(deg, bbase, row_ptr);
    build_csr_kernel<<<(N_EDGES + 255) / 256, 256, 0, stream>>>(ei, ew, slot, row_ptr, csr);
    prep_wt_kernel<<<(DEPTH * INT_F * INT_F) / 256, 256, 0, stream>>>(W_layers, WT16);

    // ---- input projection (fp16 h) ----
    gemm_in_kernel<<<N_NODES / 16, 256, 0, stream>>>(X, W_in, b_in, h16A);

    // ---- fused layers: ping-pong h16A <-> h16B; last layer also writes fp32 h ----
    __half* hin = h16A;
    __half* hout = h16B;
    for (int i = 0; i < DEPTH; ++i) {
        fused_layer_kernel<<<N_NODES / 16, 64, 0, stream>>>(
            row_ptr, csr, hin, WT16 + (size_t)i * INT_F * INT_F,
            b_layers + (size_t)i * INT_F, hout,
            (i == DEPTH - 1) ? hf32 : nullptr);
        __half* tmp = hin; hin = hout; hout = tmp;
    }

    // ---- output projection (hin == final h16 == h16A) ----
    gemm_out_kernel<<<N_NODES / 8, 256, 0, stream>>>(hin, W_out, b_out, out1);
}

// Round 11
// 295.665 us; speedup vs baseline: 1.7354x; 1.1054x over previous
//
#include <hip/hip_runtime.h>
#include <hip/hip_fp16.h>

// Simple GNN: h = X@W_in+b; 4x { agg = segmean(w*h[src], dst); h += lrelu(agg@W_l+b_l) }
// out = (h@W_out+b_out, h)
// Round 11: fused layer at 2 waves/block (128 thr, 16 nodes): gather 8 lanes/node
//           (acc 16 floats, ~80 VGPR), MFMA split by col-halves across the 2 waves.
//           Doubles resident waves (3125 -> 6250) to hide gather latency.

#define N_NODES 50000
#define N_EDGES 625000
#define IN_F 64
#define INT_F 128
#define OUT_F 32
#define DEPTH 4
#define NEG_SLOPE 0.01f

#define SCAN_BLOCKS 196  // 196*256 = 50176 >= N_NODES

typedef _Float16 half8 __attribute__((ext_vector_type(8)));
typedef float floatx4 __attribute__((ext_vector_type(4)));

// ---- in-degree + slot (slot = position of edge within its dst bucket) ----
__global__ void deg_slot_kernel(const int2* __restrict__ ei, int* __restrict__ deg,
                                int* __restrict__ slot) {
    int i = blockIdx.x * blockDim.x + threadIdx.x;
    if (i < N_EDGES) slot[i] = atomicAdd(&deg[ei[i].y], 1);
}

// ---- scan stage 1 ----
__global__ void scan1_kernel(const int* __restrict__ deg, int* __restrict__ partial) {
    int node = blockIdx.x * 256 + threadIdx.x;
    int v = (node < N_NODES) ? deg[node] : 0;
    __shared__ int sd[256];
    sd[threadIdx.x] = v;
    __syncthreads();
    for (int off = 128; off > 0; off >>= 1) {
        if (threadIdx.x < off) sd[threadIdx.x] += sd[threadIdx.x + off];
        __syncthreads();
    }
    if (threadIdx.x == 0) partial[blockIdx.x] = sd[0];
}

// ---- scan stage 2 ----
__global__ void scan2_kernel(const int* __restrict__ partial, int* __restrict__ base,
                             int* __restrict__ row_ptr) {
    __shared__ int ps[256];
    int t = threadIdx.x;
    int v = (t < SCAN_BLOCKS) ? partial[t] : 0;
    ps[t] = v;
    __syncthreads();
    for (int off = 1; off < 256; off <<= 1) {
        int add = (t >= off) ? ps[t - off] : 0;
        __syncthreads();
        ps[t] += add;
        __syncthreads();
    }
    if (t < SCAN_BLOCKS) base[t] = ps[t] - v;
    if (t == SCAN_BLOCKS - 1) row_ptr[N_NODES] = ps[t];
}

// ---- scan stage 3 ----
__global__ void scan3_kernel(const int* __restrict__ deg, const int* __restrict__ base,
                             int* __restrict__ row_ptr) {
    int node = blockIdx.x * 256 + threadIdx.x;
    int t = threadIdx.x;
    int d = (node < N_NODES) ? deg[node] : 0;
    __shared__ int ps[256];
    ps[t] = d;
    __syncthreads();
    for (int off = 1; off < 256; off <<= 1) {
        int add = (t >= off) ? ps[t - off] : 0;
        __syncthreads();
        ps[t] += add;
        __syncthreads();
    }
    if (node < N_NODES) row_ptr[node] = base[blockIdx.x] + ps[t] - d;
}

// ---- non-atomic scatter into paired CSR: csr[pos] = (src, weight_bits) ----
__global__ void build_csr_kernel(const int2* __restrict__ ei, const float* __restrict__ ew,
                                 const int* __restrict__ slot, const int* __restrict__ row_ptr,
                                 int2* __restrict__ csr) {
    int e = blockIdx.x * blockDim.x + threadIdx.x;
    if (e >= N_EDGES) return;
    int2 sd = ei[e];
    int pos = row_ptr[sd.y] + slot[e];
    csr[pos] = make_int2(sd.x, __float_as_int(ew[e]));
}

// ---- WT16[l][n][k] = fp16(W_layers[l][k][n]) ----
__global__ void prep_wt_kernel(const float* __restrict__ W_layers, _Float16* __restrict__ WT16) {
    int idx = blockIdx.x * 256 + threadIdx.x;
    int l = idx >> 14;
    int rem = idx & 16383;
    int n = rem >> 7;
    int k = rem & 127;
    WT16[idx] = (_Float16)W_layers[(size_t)l * 16384 + (size_t)k * 128 + n];
}

// ---- h16 = fp16(X @ W_in + b_in)  (16 nodes per 256-thread block) ----
__global__ void gemm_in_kernel(const float* __restrict__ X, const float* __restrict__ W,
                               const float* __restrict__ b, __half* __restrict__ h16) {
    __shared__ float xs[16][IN_F];
    const int base = blockIdx.x * 16;
    const int t = threadIdx.x;
    ((float4*)xs)[t] = ((const float4*)(X + (size_t)base * IN_F))[t];
    __syncthreads();
    const int f = t & (INT_F - 1);
    const int rg = t >> 7;
    float acc[8];
    const float bv = b[f];
#pragma unroll
    for (int j = 0; j < 8; ++j) acc[j] = bv;
#pragma unroll 4
    for (int k = 0; k < IN_F; ++k) {
        float w = W[k * INT_F + f];
#pragma unroll
        for (int j = 0; j < 8; ++j) acc[j] += xs[rg * 8 + j][k] * w;
    }
#pragma unroll
    for (int j = 0; j < 8; ++j)
        h16[(size_t)(base + rg * 8 + j) * INT_F + f] = __float2half(acc[j]);
}

// ---- fused layer: 128 thr = 2 waves = 16 nodes. gather(8 lanes/node) -> LDS -> MFMA ----
// h16_out[n] = fp16( fp32(h16_in[n]) + lrelu( segmean_n @ W + b ) ); optional fp32 out.
__global__ __launch_bounds__(128) void fused_layer_kernel(
    const int* __restrict__ row_ptr, const int2* __restrict__ csr,
    const __half* h16_in, const _Float16* __restrict__ WT16,
    const float* __restrict__ b, __half* __restrict__ h16_out,
    float* __restrict__ h_fp32_out /* null except last layer */) {
    __shared__ _Float16 as[16 * 136];  // 16 rows x 272B (128 halves + 8 pad)
    const int t = threadIdx.x;         // 0..127
    const int row0 = blockIdx.x * 16;  // 3125 * 16 == 50000, exact

    // ---- phase 1: gather. 8 lanes per node; lane covers 16 features (32B = 2 uint4). ----
    const int nl = t >> 3;  // local node 0..15
    const int sl = t & 7;   // feature eighth
    const int node = row0 + nl;
    const uint4* h16q = (const uint4*)h16_in;

    const int s = row_ptr[node], e = row_ptr[node + 1];
    float acc[16];
#pragma unroll
    for (int j = 0; j < 16; ++j) acc[j] = 0.f;

    int i = s;
    for (; i + 1 < e; i += 2) {
        int2 e0 = csr[i], e1 = csr[i + 1];
        float w0 = __int_as_float(e0.y), w1 = __int_as_float(e1.y);
        const uint4* r0 = h16q + (size_t)e0.x * 16 + sl * 2;
        const uint4* r1 = h16q + (size_t)e1.x * 16 + sl * 2;
        uint4 a0 = r0[0], a1 = r0[1];
        uint4 c0 = r1[0], c1 = r1[1];
        const __half2* ha0 = (const __half2*)&a0;
        const __half2* ha1 = (const __half2*)&a1;
        const __half2* hc0 = (const __half2*)&c0;
        const __half2* hc1 = (const __half2*)&c1;
#pragma unroll
        for (int q = 0; q < 4; ++q) {
            float2 f0 = __half22float2(ha0[q]);
            float2 f1 = __half22float2(ha1[q]);
            float2 g0 = __half22float2(hc0[q]);
            float2 g1 = __half22float2(hc1[q]);
            acc[2 * q + 0] += w0 * f0.x + w1 * g0.x;
            acc[2 * q + 1] += w0 * f0.y + w1 * g0.y;
            acc[8 + 2 * q + 0] += w0 * f1.x + w1 * g1.x;
            acc[8 + 2 * q + 1] += w0 * f1.y + w1 * g1.y;
        }
    }
    if (i < e) {
        int2 e0 = csr[i];
        float w0 = __int_as_float(e0.y);
        const uint4* r0 = h16q + (size_t)e0.x * 16 + sl * 2;
        uint4 a0 = r0[0], a1 = r0[1];
        const __half2* ha0 = (const __half2*)&a0;
        const __half2* ha1 = (const __half2*)&a1;
#pragma unroll
        for (int q = 0; q < 4; ++q) {
            float2 f0 = __half22float2(ha0[q]);
            float2 f1 = __half22float2(ha1[q]);
            acc[2 * q + 0] += w0 * f0.x;
            acc[2 * q + 1] += w0 * f0.y;
            acc[8 + 2 * q + 0] += w0 * f1.x;
            acc[8 + 2 * q + 1] += w0 * f1.y;
        }
    }
    const float inv = 1.0f / fmaxf((float)(e - s), 1.0f);

    // stage to LDS: row nl, halves [sl*16, sl*16+16), row stride 136 halves
#pragma unroll
    for (int u = 0; u < 2; ++u) {
        uint4 o;
        unsigned int* op = &o.x;
#pragma unroll
        for (int q = 0; q < 4; ++q) {
            __half2 hv = __floats2half2_rn(acc[u * 8 + 2 * q] * inv, acc[u * 8 + 2 * q + 1] * inv);
            op[q] = *(const unsigned int*)&hv;
        }
        *(uint4*)(as + nl * 136 + sl * 16 + u * 8) = o;
    }
    __syncthreads();

    // ---- phase 2: MFMA. wave wv computes col-tiles [wv*4, wv*4+4). ----
    const int wv = t >> 6;       // 0..1
    const int lane = t & 63;
    const int r = lane & 15;
    const int ksel = lane >> 4;  // 0..3

    half8 afr[4];
#pragma unroll
    for (int ks = 0; ks < 4; ++ks)
        afr[ks] = *(const half8*)(as + r * 136 + ks * 32 + ksel * 8);

    floatx4 accd[4];
#pragma unroll
    for (int c4 = 0; c4 < 4; ++c4) accd[c4] = (floatx4){0.f, 0.f, 0.f, 0.f};

#pragma unroll
    for (int c4 = 0; c4 < 4; ++c4) {
        const int ct = wv * 4 + c4;
        const _Float16* wbase = WT16 + (size_t)(ct * 16 + r) * INT_F + ksel * 8;
        half8 b0 = *(const half8*)(wbase + 0);
        half8 b1 = *(const half8*)(wbase + 32);
        half8 b2 = *(const half8*)(wbase + 64);
        half8 b3 = *(const half8*)(wbase + 96);
        accd[c4] = __builtin_amdgcn_mfma_f32_16x16x32_f16(afr[0], b0, accd[c4], 0, 0, 0);
        accd[c4] = __builtin_amdgcn_mfma_f32_16x16x32_f16(afr[1], b1, accd[c4], 0, 0, 0);
        accd[c4] = __builtin_amdgcn_mfma_f32_16x16x32_f16(afr[2], b2, accd[c4], 0, 0, 0);
        accd[c4] = __builtin_amdgcn_mfma_f32_16x16x32_f16(afr[3], b3, accd[c4], 0, 0, 0);
    }

    // ---- phase 3: epilogue. D[row][col]: col = ct*16 + r, row = row0 + ksel*4 + reg ----
#pragma unroll
    for (int c4 = 0; c4 < 4; ++c4) {
        const int ct = wv * 4 + c4;
        int col = ct * 16 + r;
        float bias = b[col];
#pragma unroll
        for (int reg = 0; reg < 4; ++reg) {
            int row = row0 + ksel * 4 + reg;
            size_t idx = (size_t)row * INT_F + col;
            float z = accd[c4][reg] + bias;
            float nh = __half2float(h16_in[idx]) + ((z >= 0.f) ? z : NEG_SLOPE * z);
            h16_out[idx] = __float2half(nh);
            if (h_fp32_out) h_fp32_out[idx] = nh;
        }
    }
}

// ---- out = h16 @ W_out + b_out  (8 nodes per 256-thread block) ----
__global__ void gemm_out_kernel(const __half* __restrict__ h16, const float* __restrict__ W,
                                const float* __restrict__ b, float* __restrict__ out) {
    __shared__ float hr[8][INT_F];
    const int base = blockIdx.x * 8;  // 6250 * 8 == 50000, exact
    const int t = threadIdx.x;
    if (t < 128) {
        int n = t >> 4, part = t & 15;
        uint4 v = ((const uint4*)h16)[(size_t)(base + n) * 16 + part];
        const __half2* hp = (const __half2*)&v;
        float* dst = &hr[n][part * 8];
#pragma unroll
        for (int q = 0; q < 4; ++q) {
            float2 f = __half22float2(hp[q]);
            dst[2 * q] = f.x;
            dst[2 * q + 1] = f.y;
        }
    }
    __syncthreads();
    int nl = t >> 5;          // 0..7
    int f = t & 31;           // 0..31
    int node = base + nl;
    float acc = b[f];
#pragma unroll 8
    for (int k = 0; k < INT_F; ++k) acc += hr[nl][k] * W[k * OUT_F + f];
    out[(size_t)node * OUT_F + f] = acc;
}

extern "C" void kernel_launch(void* const* d_in, const int* in_sizes, int n_in,
                              void* d_out, int out_size, void* d_ws, size_t ws_size,
                              hipStream_t stream) {
    const float* X        = (const float*)d_in[0];
    const int2*  ei       = (const int2*)d_in[1];
    const float* ew       = (const float*)d_in[2];
    const float* W_in     = (const float*)d_in[3];
    const float* b_in     = (const float*)d_in[4];
    const float* W_layers = (const float*)d_in[5];
    const float* b_layers = (const float*)d_in[6];
    const float* W_out    = (const float*)d_in[7];
    const float* b_out    = (const float*)d_in[8];

    float* out1 = (float*)d_out;
    float* hf32 = out1 + (size_t)N_NODES * OUT_F;  // fp32 h output (written by last layer)

    // workspace layout (~34 MB); 16B alignment maintained
    char* ws = (char*)d_ws;
    __half*   h16A  = (__half*)ws;    ws += (size_t)N_NODES * INT_F * 2;        // 12.8 MB
    __half*   h16B  = (__half*)ws;    ws += (size_t)N_NODES * INT_F * 2;        // 12.8 MB
    _Float16* WT16  = (_Float16*)ws;  ws += (size_t)DEPTH * INT_F * INT_F * 2;  // 128 KB
    int2* csr     = (int2*)ws;  ws += (size_t)N_EDGES * 8;                      // 5 MB
    int*  slot    = (int*)ws;   ws += (size_t)N_EDGES * 4;                      // 2.5 MB
    int*  row_ptr = (int*)ws;   ws += (size_t)(N_NODES + 1) * 4;
    int*  deg     = (int*)ws;   ws += (size_t)N_NODES * 4;
    int*  partial = (int*)ws;   ws += (size_t)SCAN_BLOCKS * 4;
    int*  bbase   = (int*)ws;   ws += (size_t)SCAN_BLOCKS * 4;

    // ---- build CSR + transpose weights (once per call) ----
    (void)hipMemsetAsync(deg, 0, (size_t)N_NODES * 4, stream);
    deg_slot_kernel<<<(N_EDGES + 255) / 256, 256, 0, stream>>>(ei, deg, slot);
    scan1_kernel<<<SCAN_BLOCKS, 256, 0, stream>>>(deg, partial);
    scan2_kernel<<<1, 256, 0, stream>>>(partial, bbase, row_ptr);
    scan3_kernel<<<SCAN_BLOCKS, 256, 0, stream>>>(deg, bbase, row_ptr);
    build_csr_kernel<<<(N_EDGES + 255) / 256, 256, 0, stream>>>(ei, ew, slot, row_ptr, csr);
    prep_wt_kernel<<<(DEPTH * INT_F * INT_F) / 256, 256, 0, stream>>>(W_layers, WT16);

    // ---- input projection (fp16 h) ----
    gemm_in_kernel<<<N_NODES / 16, 256, 0, stream>>>(X, W_in, b_in, h16A);

    // ---- fused layers: ping-pong h16A <-> h16B; last layer also writes fp32 h ----
    __half* hin = h16A;
    __half* hout = h16B;
    for (int i = 0; i < DEPTH; ++i) {
        fused_layer_kernel<<<N_NODES / 16, 128, 0, stream>>>(
            row_ptr, csr, hin, WT16 + (size_t)i * INT_F * INT_F,
            b_layers + (size_t)i * INT_F, hout,
            (i == DEPTH - 1) ? hf32 : nullptr);
        __half* tmp = hin; hin = hout; hout = tmp;
    }

    // ---- output projection (hin == final h16 == h16A) ----
    gemm_out_kernel<<<N_NODES / 8, 256, 0, stream>>>(hin, W_out, b_out, out1);
}

// Round 12
// 265.647 us; speedup vs baseline: 1.9315x; 1.1130x over previous
//
#include <hip/hip_runtime.h>
#include <hip/hip_fp16.h>

// Simple GNN: h = X@W_in+b; 4x { agg = segmean(w*h[src], dst); h += lrelu(agg@W_l+b_l) }
// out = (h@W_out+b_out, h)
// Round 12: fused layer at 4 waves/block (256 thr, 16 nodes, 16 lanes/node gather ->
//           12500 waves total) + LDS-transpose epilogue (coalesced residual read and
//           full-line h16/fp32 stores; kills the 4.4x write amplification).

#define N_NODES 50000
#define N_EDGES 625000
#define IN_F 64
#define INT_F 128
#define OUT_F 32
#define DEPTH 4
#define NEG_SLOPE 0.01f

#define SCAN_BLOCKS 196  // 196*256 = 50176 >= N_NODES

typedef _Float16 half8 __attribute__((ext_vector_type(8)));
typedef float floatx4 __attribute__((ext_vector_type(4)));

// ---- in-degree + slot (slot = position of edge within its dst bucket) ----
__global__ void deg_slot_kernel(const int2* __restrict__ ei, int* __restrict__ deg,
                                int* __restrict__ slot) {
    int i = blockIdx.x * blockDim.x + threadIdx.x;
    if (i < N_EDGES) slot[i] = atomicAdd(&deg[ei[i].y], 1);
}

// ---- scan stage 1 ----
__global__ void scan1_kernel(const int* __restrict__ deg, int* __restrict__ partial) {
    int node = blockIdx.x * 256 + threadIdx.x;
    int v = (node < N_NODES) ? deg[node] : 0;
    __shared__ int sd[256];
    sd[threadIdx.x] = v;
    __syncthreads();
    for (int off = 128; off > 0; off >>= 1) {
        if (threadIdx.x < off) sd[threadIdx.x] += sd[threadIdx.x + off];
        __syncthreads();
    }
    if (threadIdx.x == 0) partial[blockIdx.x] = sd[0];
}

// ---- scan stage 2 ----
__global__ void scan2_kernel(const int* __restrict__ partial, int* __restrict__ base,
                             int* __restrict__ row_ptr) {
    __shared__ int ps[256];
    int t = threadIdx.x;
    int v = (t < SCAN_BLOCKS) ? partial[t] : 0;
    ps[t] = v;
    __syncthreads();
    for (int off = 1; off < 256; off <<= 1) {
        int add = (t >= off) ? ps[t - off] : 0;
        __syncthreads();
        ps[t] += add;
        __syncthreads();
    }
    if (t < SCAN_BLOCKS) base[t] = ps[t] - v;
    if (t == SCAN_BLOCKS - 1) row_ptr[N_NODES] = ps[t];
}

// ---- scan stage 3 ----
__global__ void scan3_kernel(const int* __restrict__ deg, const int* __restrict__ base,
                             int* __restrict__ row_ptr) {
    int node = blockIdx.x * 256 + threadIdx.x;
    int t = threadIdx.x;
    int d = (node < N_NODES) ? deg[node] : 0;
    __shared__ int ps[256];
    ps[t] = d;
    __syncthreads();
    for (int off = 1; off < 256; off <<= 1) {
        int add = (t >= off) ? ps[t - off] : 0;
        __syncthreads();
        ps[t] += add;
        __syncthreads();
    }
    if (node < N_NODES) row_ptr[node] = base[blockIdx.x] + ps[t] - d;
}

// ---- non-atomic scatter into paired CSR: csr[pos] = (src, weight_bits) ----
__global__ void build_csr_kernel(const int2* __restrict__ ei, const float* __restrict__ ew,
                                 const int* __restrict__ slot, const int* __restrict__ row_ptr,
                                 int2* __restrict__ csr) {
    int e = blockIdx.x * blockDim.x + threadIdx.x;
    if (e >= N_EDGES) return;
    int2 sd = ei[e];
    int pos = row_ptr[sd.y] + slot[e];
    csr[pos] = make_int2(sd.x, __float_as_int(ew[e]));
}

// ---- WT16[l][n][k] = fp16(W_layers[l][k][n]) ----
__global__ void prep_wt_kernel(const float* __restrict__ W_layers, _Float16* __restrict__ WT16) {
    int idx = blockIdx.x * 256 + threadIdx.x;
    int l = idx >> 14;
    int rem = idx & 16383;
    int n = rem >> 7;
    int k = rem & 127;
    WT16[idx] = (_Float16)W_layers[(size_t)l * 16384 + (size_t)k * 128 + n];
}

// ---- h16 = fp16(X @ W_in + b_in)  (16 nodes per 256-thread block) ----
__global__ void gemm_in_kernel(const float* __restrict__ X, const float* __restrict__ W,
                               const float* __restrict__ b, __half* __restrict__ h16) {
    __shared__ float xs[16][IN_F];
    const int base = blockIdx.x * 16;
    const int t = threadIdx.x;
    ((float4*)xs)[t] = ((const float4*)(X + (size_t)base * IN_F))[t];
    __syncthreads();
    const int f = t & (INT_F - 1);
    const int rg = t >> 7;
    float acc[8];
    const float bv = b[f];
#pragma unroll
    for (int j = 0; j < 8; ++j) acc[j] = bv;
#pragma unroll 4
    for (int k = 0; k < IN_F; ++k) {
        float w = W[k * INT_F + f];
#pragma unroll
        for (int j = 0; j < 8; ++j) acc[j] += xs[rg * 8 + j][k] * w;
    }
#pragma unroll
    for (int j = 0; j < 8; ++j)
        h16[(size_t)(base + rg * 8 + j) * INT_F + f] = __float2half(acc[j]);
}

// ---- fused layer: 256 thr = 4 waves = 16 nodes; 16 lanes/node gather -> LDS -> MFMA ----
// h16_out[n] = fp16( fp32(h16_in[n]) + lrelu( segmean_n @ W + b ) ); optional fp32 out.
__global__ __launch_bounds__(256) void fused_layer_kernel(
    const int* __restrict__ row_ptr, const int2* __restrict__ csr,
    const __half* h16_in, const _Float16* __restrict__ WT16,
    const float* __restrict__ b, __half* __restrict__ h16_out,
    float* __restrict__ h_fp32_out /* null except last layer */) {
    __shared__ _Float16 as[16 * 136];  // 16 rows x 272B (128 halves + 8 pad)
    const int t = threadIdx.x;         // 0..255
    const int row0 = blockIdx.x * 16;  // 3125 * 16 == 50000, exact

    // ---- phase 1: gather. 16 lanes per node; lane covers 8 features (16B = 1 uint4). ----
    const int nl = t >> 4;  // local node 0..15
    const int sl = t & 15;  // feature sixteenth
    const int node = row0 + nl;
    const uint4* h16q = (const uint4*)h16_in;

    const int s = row_ptr[node], e = row_ptr[node + 1];
    float acc[8];
#pragma unroll
    for (int j = 0; j < 8; ++j) acc[j] = 0.f;

    int i = s;
    for (; i + 1 < e; i += 2) {
        int2 e0 = csr[i], e1 = csr[i + 1];
        float w0 = __int_as_float(e0.y), w1 = __int_as_float(e1.y);
        uint4 a = h16q[(size_t)e0.x * 16 + sl];
        uint4 c = h16q[(size_t)e1.x * 16 + sl];
        const __half2* ha = (const __half2*)&a;
        const __half2* hc = (const __half2*)&c;
#pragma unroll
        for (int q = 0; q < 4; ++q) {
            float2 fa = __half22float2(ha[q]);
            float2 fc = __half22float2(hc[q]);
            acc[2 * q + 0] += w0 * fa.x + w1 * fc.x;
            acc[2 * q + 1] += w0 * fa.y + w1 * fc.y;
        }
    }
    if (i < e) {
        int2 e0 = csr[i];
        float w0 = __int_as_float(e0.y);
        uint4 a = h16q[(size_t)e0.x * 16 + sl];
        const __half2* ha = (const __half2*)&a;
#pragma unroll
        for (int q = 0; q < 4; ++q) {
            float2 fa = __half22float2(ha[q]);
            acc[2 * q + 0] += w0 * fa.x;
            acc[2 * q + 1] += w0 * fa.y;
        }
    }
    const float inv = 1.0f / fmaxf((float)(e - s), 1.0f);

    // stage to LDS: row nl, halves [sl*8, sl*8+8), row stride 136 halves
    {
        uint4 o;
        unsigned int* op = &o.x;
#pragma unroll
        for (int q = 0; q < 4; ++q) {
            __half2 hv = __floats2half2_rn(acc[2 * q] * inv, acc[2 * q + 1] * inv);
            op[q] = *(const unsigned int*)&hv;
        }
        *(uint4*)(as + nl * 136 + sl * 8) = o;
    }
    __syncthreads();

    // ---- phase 2: MFMA. wave wv computes col-tiles [wv*2, wv*2+2). ----
    const int wv = t >> 6;       // 0..3
    const int lane = t & 63;
    const int r = lane & 15;
    const int ksel = lane >> 4;  // 0..3

    half8 afr[4];
#pragma unroll
    for (int ks = 0; ks < 4; ++ks)
        afr[ks] = *(const half8*)(as + r * 136 + ks * 32 + ksel * 8);

    floatx4 accd[2];
#pragma unroll
    for (int c4 = 0; c4 < 2; ++c4) accd[c4] = (floatx4){0.f, 0.f, 0.f, 0.f};

#pragma unroll
    for (int c4 = 0; c4 < 2; ++c4) {
        const int ct = wv * 2 + c4;
        const _Float16* wbase = WT16 + (size_t)(ct * 16 + r) * INT_F + ksel * 8;
        half8 b0 = *(const half8*)(wbase + 0);
        half8 b1 = *(const half8*)(wbase + 32);
        half8 b2 = *(const half8*)(wbase + 64);
        half8 b3 = *(const half8*)(wbase + 96);
        accd[c4] = __builtin_amdgcn_mfma_f32_16x16x32_f16(afr[0], b0, accd[c4], 0, 0, 0);
        accd[c4] = __builtin_amdgcn_mfma_f32_16x16x32_f16(afr[1], b1, accd[c4], 0, 0, 0);
        accd[c4] = __builtin_amdgcn_mfma_f32_16x16x32_f16(afr[2], b2, accd[c4], 0, 0, 0);
        accd[c4] = __builtin_amdgcn_mfma_f32_16x16x32_f16(afr[3], b3, accd[c4], 0, 0, 0);
    }

    // ---- phase 3a: bias + lrelu in fp32, write activation back to LDS (fp16) ----
    __syncthreads();  // all waves done reading A-fragments
#pragma unroll
    for (int c4 = 0; c4 < 2; ++c4) {
        const int ct = wv * 2 + c4;
        const int col = ct * 16 + r;
        const float bias = b[col];
#pragma unroll
        for (int reg = 0; reg < 4; ++reg) {
            const int rowl = ksel * 4 + reg;  // 0..15
            float z = accd[c4][reg] + bias;
            float a = (z >= 0.f) ? z : NEG_SLOPE * z;
            as[rowl * 136 + col] = (_Float16)a;
        }
    }
    __syncthreads();

    // ---- phase 3b: coalesced residual + store. thread t: row t>>4, halves [(t&15)*8, +8) ----
    {
        const int rowl = t >> 4;
        const int part = t & 15;
        const int row = row0 + rowl;
        uint4 av = *(const uint4*)(as + rowl * 136 + part * 8);
        uint4 hv = h16q[(size_t)row * 16 + part];  // coalesced
        const __half2* ap = (const __half2*)&av;
        const __half2* hp = (const __half2*)&hv;
        uint4 o;
        unsigned int* op = &o.x;
        float nh[8];
#pragma unroll
        for (int q = 0; q < 4; ++q) {
            float2 fa = __half22float2(ap[q]);
            float2 fh = __half22float2(hp[q]);
            nh[2 * q + 0] = fh.x + fa.x;
            nh[2 * q + 1] = fh.y + fa.y;
            __half2 hv2 = __floats2half2_rn(nh[2 * q], nh[2 * q + 1]);
            op[q] = *(const unsigned int*)&hv2;
        }
        ((uint4*)h16_out)[(size_t)row * 16 + part] = o;  // full-line coalesced
        if (h_fp32_out) {
            float4* f4 = (float4*)(h_fp32_out + (size_t)row * INT_F + part * 8);
            f4[0] = make_float4(nh[0], nh[1], nh[2], nh[3]);
            f4[1] = make_float4(nh[4], nh[5], nh[6], nh[7]);
        }
    }
}

// ---- out = h16 @ W_out + b_out  (8 nodes per 256-thread block) ----
__global__ void gemm_out_kernel(const __half* __restrict__ h16, const float* __restrict__ W,
                                const float* __restrict__ b, float* __restrict__ out) {
    __shared__ float hr[8][INT_F];
    const int base = blockIdx.x * 8;  // 6250 * 8 == 50000, exact
    const int t = threadIdx.x;
    if (t < 128) {
        int n = t >> 4, part = t & 15;
        uint4 v = ((const uint4*)h16)[(size_t)(base + n) * 16 + part];
        const __half2* hp = (const __half2*)&v;
        float* dst = &hr[n][part * 8];
#pragma unroll
        for (int q = 0; q < 4; ++q) {
            float2 f = __half22float2(hp[q]);
            dst[2 * q] = f.x;
            dst[2 * q + 1] = f.y;
        }
    }
    __syncthreads();
    int nl = t >> 5;          // 0..7
    int f = t & 31;           // 0..31
    int node = base + nl;
    float acc = b[f];
#pragma unroll 8
    for (int k = 0; k < INT_F; ++k) acc += hr[nl][k] * W[k * OUT_F + f];
    out[(size_t)node * OUT_F + f] = acc;
}

extern "C" void kernel_launch(void* const* d_in, const int* in_sizes, int n_in,
                              void* d_out, int out_size, void* d_ws, size_t ws_size,
                              hipStream_t stream) {
    const float* X        = (const float*)d_in[0];
    const int2*  ei       = (const int2*)d_in[1];
    const float* ew       = (const float*)d_in[2];
    const float* W_in     = (const float*)d_in[3];
    const float* b_in     = (const float*)d_in[4];
    const float* W_layers = (const float*)d_in[5];
    const float* b_layers = (const float*)d_in[6];
    const float* W_out    = (const float*)d_in[7];
    const float* b_out    = (const float*)d_in[8];

    float* out1 = (float*)d_out;
    float* hf32 = out1 + (size_t)N_NODES * OUT_F;  // fp32 h output (written by last layer)

    // workspace layout (~34 MB); 16B alignment maintained
    char* ws = (char*)d_ws;
    __half*   h16A  = (__half*)ws;    ws += (size_t)N_NODES * INT_F * 2;        // 12.8 MB
    __half*   h16B  = (__half*)ws;    ws += (size_t)N_NODES * INT_F * 2;        // 12.8 MB
    _Float16* WT16  = (_Float16*)ws;  ws += (size_t)DEPTH * INT_F * INT_F * 2;  // 128 KB
    int2* csr     = (int2*)ws;  ws += (size_t)N_EDGES * 8;                      // 5 MB
    int*  slot    = (int*)ws;   ws += (size_t)N_EDGES * 4;                      // 2.5 MB
    int*  row_ptr = (int*)ws;   ws += (size_t)(N_NODES + 1) * 4;
    int*  deg     = (int*)ws;   ws += (size_t)N_NODES * 4;
    int*  partial = (int*)ws;   ws += (size_t)SCAN_BLOCKS * 4;
    int*  bbase   = (int*)ws;   ws += (size_t)SCAN_BLOCKS * 4;

    // ---- build CSR + transpose weights (once per call) ----
    (void)hipMemsetAsync(deg, 0, (size_t)N_NODES * 4, stream);
    deg_slot_kernel<<<(N_EDGES + 255) / 256, 256, 0, stream>>>(ei, deg, slot);
    scan1_kernel<<<SCAN_BLOCKS, 256, 0, stream>>>(deg, partial);
    scan2_kernel<<<1, 256, 0, stream>>>(partial, bbase, row_ptr);
    scan3_kernel<<<SCAN_BLOCKS, 256, 0, stream>>>(deg, bbase, row_ptr);
    build_csr_kernel<<<(N_EDGES + 255) / 256, 256, 0, stream>>>(ei, ew, slot, row_ptr, csr);
    prep_wt_kernel<<<(DEPTH * INT_F * INT_F) / 256, 256, 0, stream>>>(W_layers, WT16);

    // ---- input projection (fp16 h) ----
    gemm_in_kernel<<<N_NODES / 16, 256, 0, stream>>>(X, W_in, b_in, h16A);

    // ---- fused layers: ping-pong h16A <-> h16B; last layer also writes fp32 h ----
    __half* hin = h16A;
    __half* hout = h16B;
    for (int i = 0; i < DEPTH; ++i) {
        fused_layer_kernel<<<N_NODES / 16, 256, 0, stream>>>(
            row_ptr, csr, hin, WT16 + (size_t)i * INT_F * INT_F,
            b_layers + (size_t)i * INT_F, hout,
            (i == DEPTH - 1) ? hf32 : nullptr);
        __half* tmp = hin; hin = hout; hout = tmp;
    }

    // ---- output projection (hin == final h16 == h16A) ----
    gemm_out_kernel<<<N_NODES / 8, 256, 0, stream>>>(hin, W_out, b_out, out1);
}

// Round 13
// 248.175 us; speedup vs baseline: 2.0675x; 1.0704x over previous
//
#include <hip/hip_runtime.h>
#include <hip/hip_fp16.h>

// Simple GNN: h = X@W_in+b; 4x { agg = segmean(w*h[src], dst); h += lrelu(agg@W_l+b_l) }
// out = (h@W_out+b_out, h)
// Round 13: packed 4B CSR entries (src:16 | fp16 w:16), 4-edge-unrolled gather with
//           fp16 packed accumulate (__hfma2), LDS-transpose epilogue kept from r12.

#define N_NODES 50000
#define N_EDGES 625000
#define IN_F 64
#define INT_F 128
#define OUT_F 32
#define DEPTH 4
#define NEG_SLOPE 0.01f

#define SCAN_BLOCKS 196  // 196*256 = 50176 >= N_NODES

typedef _Float16 half8 __attribute__((ext_vector_type(8)));
typedef float floatx4 __attribute__((ext_vector_type(4)));

// ---- in-degree + slot (slot = position of edge within its dst bucket) ----
__global__ void deg_slot_kernel(const int2* __restrict__ ei, int* __restrict__ deg,
                                int* __restrict__ slot) {
    int i = blockIdx.x * blockDim.x + threadIdx.x;
    if (i < N_EDGES) slot[i] = atomicAdd(&deg[ei[i].y], 1);
}

// ---- scan stage 1 ----
__global__ void scan1_kernel(const int* __restrict__ deg, int* __restrict__ partial) {
    int node = blockIdx.x * 256 + threadIdx.x;
    int v = (node < N_NODES) ? deg[node] : 0;
    __shared__ int sd[256];
    sd[threadIdx.x] = v;
    __syncthreads();
    for (int off = 128; off > 0; off >>= 1) {
        if (threadIdx.x < off) sd[threadIdx.x] += sd[threadIdx.x + off];
        __syncthreads();
    }
    if (threadIdx.x == 0) partial[blockIdx.x] = sd[0];
}

// ---- scan stage 2 ----
__global__ void scan2_kernel(const int* __restrict__ partial, int* __restrict__ base,
                             int* __restrict__ row_ptr) {
    __shared__ int ps[256];
    int t = threadIdx.x;
    int v = (t < SCAN_BLOCKS) ? partial[t] : 0;
    ps[t] = v;
    __syncthreads();
    for (int off = 1; off < 256; off <<= 1) {
        int add = (t >= off) ? ps[t - off] : 0;
        __syncthreads();
        ps[t] += add;
        __syncthreads();
    }
    if (t < SCAN_BLOCKS) base[t] = ps[t] - v;
    if (t == SCAN_BLOCKS - 1) row_ptr[N_NODES] = ps[t];
}

// ---- scan stage 3 ----
__global__ void scan3_kernel(const int* __restrict__ deg, const int* __restrict__ base,
                             int* __restrict__ row_ptr) {
    int node = blockIdx.x * 256 + threadIdx.x;
    int t = threadIdx.x;
    int d = (node < N_NODES) ? deg[node] : 0;
    __shared__ int ps[256];
    ps[t] = d;
    __syncthreads();
    for (int off = 1; off < 256; off <<= 1) {
        int add = (t >= off) ? ps[t - off] : 0;
        __syncthreads();
        ps[t] += add;
        __syncthreads();
    }
    if (node < N_NODES) row_ptr[node] = base[blockIdx.x] + ps[t] - d;
}

// ---- non-atomic scatter into packed CSR: csru[pos] = (fp16(w)<<16) | src ----
__global__ void build_csr_kernel(const int2* __restrict__ ei, const float* __restrict__ ew,
                                 const int* __restrict__ slot, const int* __restrict__ row_ptr,
                                 unsigned int* __restrict__ csru) {
    int e = blockIdx.x * blockDim.x + threadIdx.x;
    if (e >= N_EDGES) return;
    int2 sd = ei[e];
    int pos = row_ptr[sd.y] + slot[e];
    unsigned short wh = __half_as_ushort(__float2half(ew[e]));
    csru[pos] = (unsigned int)sd.x | ((unsigned int)wh << 16);  // src < 65536
}

// ---- WT16[l][n][k] = fp16(W_layers[l][k][n]) ----
__global__ void prep_wt_kernel(const float* __restrict__ W_layers, _Float16* __restrict__ WT16) {
    int idx = blockIdx.x * 256 + threadIdx.x;
    int l = idx >> 14;
    int rem = idx & 16383;
    int n = rem >> 7;
    int k = rem & 127;
    WT16[idx] = (_Float16)W_layers[(size_t)l * 16384 + (size_t)k * 128 + n];
}

// ---- h16 = fp16(X @ W_in + b_in)  (16 nodes per 256-thread block) ----
__global__ void gemm_in_kernel(const float* __restrict__ X, const float* __restrict__ W,
                               const float* __restrict__ b, __half* __restrict__ h16) {
    __shared__ float xs[16][IN_F];
    const int base = blockIdx.x * 16;
    const int t = threadIdx.x;
    ((float4*)xs)[t] = ((const float4*)(X + (size_t)base * IN_F))[t];
    __syncthreads();
    const int f = t & (INT_F - 1);
    const int rg = t >> 7;
    float acc[8];
    const float bv = b[f];
#pragma unroll
    for (int j = 0; j < 8; ++j) acc[j] = bv;
#pragma unroll 4
    for (int k = 0; k < IN_F; ++k) {
        float w = W[k * INT_F + f];
#pragma unroll
        for (int j = 0; j < 8; ++j) acc[j] += xs[rg * 8 + j][k] * w;
    }
#pragma unroll
    for (int j = 0; j < 8; ++j)
        h16[(size_t)(base + rg * 8 + j) * INT_F + f] = __float2half(acc[j]);
}

// ---- fused layer: 256 thr = 4 waves = 16 nodes; 16 lanes/node gather -> LDS -> MFMA ----
__global__ __launch_bounds__(256) void fused_layer_kernel(
    const int* __restrict__ row_ptr, const unsigned int* __restrict__ csru,
    const __half* h16_in, const _Float16* __restrict__ WT16,
    const float* __restrict__ b, __half* __restrict__ h16_out,
    float* __restrict__ h_fp32_out /* null except last layer */) {
    __shared__ _Float16 as[16 * 136];  // 16 rows x 272B (128 halves + 8 pad)
    const int t = threadIdx.x;         // 0..255
    const int row0 = blockIdx.x * 16;  // 3125 * 16 == 50000, exact

    // ---- phase 1: gather. 16 lanes/node; lane covers 8 features (1 uint4). ----
    const int nl = t >> 4;  // local node 0..15
    const int sl = t & 15;  // feature sixteenth
    const int node = row0 + nl;
    const uint4* h16q = (const uint4*)h16_in;

    const int s = row_ptr[node], e = row_ptr[node + 1];
    __half2 acc2[4];
    const __half2 zero2 = __floats2half2_rn(0.f, 0.f);
#pragma unroll
    for (int q = 0; q < 4; ++q) acc2[q] = zero2;

    int i = s;
    for (; i + 3 < e; i += 4) {  // 4 independent row loads in flight
        unsigned int u0 = csru[i], u1 = csru[i + 1], u2 = csru[i + 2], u3 = csru[i + 3];
        uint4 r0 = h16q[(size_t)(u0 & 0xFFFFu) * 16 + sl];
        uint4 r1 = h16q[(size_t)(u1 & 0xFFFFu) * 16 + sl];
        uint4 r2 = h16q[(size_t)(u2 & 0xFFFFu) * 16 + sl];
        uint4 r3 = h16q[(size_t)(u3 & 0xFFFFu) * 16 + sl];
        __half2 w0 = __half2half2(__ushort_as_half((unsigned short)(u0 >> 16)));
        __half2 w1 = __half2half2(__ushort_as_half((unsigned short)(u1 >> 16)));
        __half2 w2 = __half2half2(__ushort_as_half((unsigned short)(u2 >> 16)));
        __half2 w3 = __half2half2(__ushort_as_half((unsigned short)(u3 >> 16)));
        const __half2* p0 = (const __half2*)&r0;
        const __half2* p1 = (const __half2*)&r1;
        const __half2* p2 = (const __half2*)&r2;
        const __half2* p3 = (const __half2*)&r3;
#pragma unroll
        for (int q = 0; q < 4; ++q) {
            acc2[q] = __hfma2(w0, p0[q], acc2[q]);
            acc2[q] = __hfma2(w1, p1[q], acc2[q]);
            acc2[q] = __hfma2(w2, p2[q], acc2[q]);
            acc2[q] = __hfma2(w3, p3[q], acc2[q]);
        }
    }
    for (; i < e; ++i) {
        unsigned int u0 = csru[i];
        uint4 r0 = h16q[(size_t)(u0 & 0xFFFFu) * 16 + sl];
        __half2 w0 = __half2half2(__ushort_as_half((unsigned short)(u0 >> 16)));
        const __half2* p0 = (const __half2*)&r0;
#pragma unroll
        for (int q = 0; q < 4; ++q) acc2[q] = __hfma2(w0, p0[q], acc2[q]);
    }
    const float inv = 1.0f / fmaxf((float)(e - s), 1.0f);

    // mean in fp32, stage to LDS: row nl, halves [sl*8, +8), row stride 136
    {
        uint4 o;
        unsigned int* op = &o.x;
#pragma unroll
        for (int q = 0; q < 4; ++q) {
            float2 f = __half22float2(acc2[q]);
            __half2 hv = __floats2half2_rn(f.x * inv, f.y * inv);
            op[q] = *(const unsigned int*)&hv;
        }
        *(uint4*)(as + nl * 136 + sl * 8) = o;
    }
    __syncthreads();

    // ---- phase 2: MFMA. wave wv computes col-tiles [wv*2, wv*2+2). ----
    const int wv = t >> 6;       // 0..3
    const int lane = t & 63;
    const int r = lane & 15;
    const int ksel = lane >> 4;  // 0..3

    half8 afr[4];
#pragma unroll
    for (int ks = 0; ks < 4; ++ks)
        afr[ks] = *(const half8*)(as + r * 136 + ks * 32 + ksel * 8);

    floatx4 accd[2];
#pragma unroll
    for (int c4 = 0; c4 < 2; ++c4) accd[c4] = (floatx4){0.f, 0.f, 0.f, 0.f};

#pragma unroll
    for (int c4 = 0; c4 < 2; ++c4) {
        const int ct = wv * 2 + c4;
        const _Float16* wbase = WT16 + (size_t)(ct * 16 + r) * INT_F + ksel * 8;
        half8 b0 = *(const half8*)(wbase + 0);
        half8 b1 = *(const half8*)(wbase + 32);
        half8 b2 = *(const half8*)(wbase + 64);
        half8 b3 = *(const half8*)(wbase + 96);
        accd[c4] = __builtin_amdgcn_mfma_f32_16x16x32_f16(afr[0], b0, accd[c4], 0, 0, 0);
        accd[c4] = __builtin_amdgcn_mfma_f32_16x16x32_f16(afr[1], b1, accd[c4], 0, 0, 0);
        accd[c4] = __builtin_amdgcn_mfma_f32_16x16x32_f16(afr[2], b2, accd[c4], 0, 0, 0);
        accd[c4] = __builtin_amdgcn_mfma_f32_16x16x32_f16(afr[3], b3, accd[c4], 0, 0, 0);
    }

    // ---- phase 3a: bias + lrelu in fp32, write activation back to LDS (fp16) ----
    __syncthreads();  // all waves done reading A-fragments
#pragma unroll
    for (int c4 = 0; c4 < 2; ++c4) {
        const int ct = wv * 2 + c4;
        const int col = ct * 16 + r;
        const float bias = b[col];
#pragma unroll
        for (int reg = 0; reg < 4; ++reg) {
            const int rowl = ksel * 4 + reg;  // 0..15
            float z = accd[c4][reg] + bias;
            float a = (z >= 0.f) ? z : NEG_SLOPE * z;
            as[rowl * 136 + col] = (_Float16)a;
        }
    }
    __syncthreads();

    // ---- phase 3b: coalesced residual + full-line stores ----
    {
        const int rowl = t >> 4;
        const int part = t & 15;
        const int row = row0 + rowl;
        uint4 av = *(const uint4*)(as + rowl * 136 + part * 8);
        uint4 hv = h16q[(size_t)row * 16 + part];  // coalesced
        const __half2* ap = (const __half2*)&av;
        const __half2* hp = (const __half2*)&hv;
        uint4 o;
        unsigned int* op = &o.x;
        float nh[8];
#pragma unroll
        for (int q = 0; q < 4; ++q) {
            float2 fa = __half22float2(ap[q]);
            float2 fh = __half22float2(hp[q]);
            nh[2 * q + 0] = fh.x + fa.x;
            nh[2 * q + 1] = fh.y + fa.y;
            __half2 hv2 = __floats2half2_rn(nh[2 * q], nh[2 * q + 1]);
            op[q] = *(const unsigned int*)&hv2;
        }
        ((uint4*)h16_out)[(size_t)row * 16 + part] = o;
        if (h_fp32_out) {
            float4* f4 = (float4*)(h_fp32_out + (size_t)row * INT_F + part * 8);
            f4[0] = make_float4(nh[0], nh[1], nh[2], nh[3]);
            f4[1] = make_float4(nh[4], nh[5], nh[6], nh[7]);
        }
    }
}

// ---- out = h16 @ W_out + b_out  (8 nodes per 256-thread block) ----
__global__ void gemm_out_kernel(const __half* __restrict__ h16, const float* __restrict__ W,
                                const float* __restrict__ b, float* __restrict__ out) {
    __shared__ float hr[8][INT_F];
    const int base = blockIdx.x * 8;  // 6250 * 8 == 50000, exact
    const int t = threadIdx.x;
    if (t < 128) {
        int n = t >> 4, part = t & 15;
        uint4 v = ((const uint4*)h16)[(size_t)(base + n) * 16 + part];
        const __half2* hp = (const __half2*)&v;
        float* dst = &hr[n][part * 8];
#pragma unroll
        for (int q = 0; q < 4; ++q) {
            float2 f = __half22float2(hp[q]);
            dst[2 * q] = f.x;
            dst[2 * q + 1] = f.y;
        }
    }
    __syncthreads();
    int nl = t >> 5;          // 0..7
    int f = t & 31;           // 0..31
    int node = base + nl;
    float acc = b[f];
#pragma unroll 8
    for (int k = 0; k < INT_F; ++k) acc += hr[nl][k] * W[k * OUT_F + f];
    out[(size_t)node * OUT_F + f] = acc;
}

extern "C" void kernel_launch(void* const* d_in, const int* in_sizes, int n_in,
                              void* d_out, int out_size, void* d_ws, size_t ws_size,
                              hipStream_t stream) {
    const float* X        = (const float*)d_in[0];
    const int2*  ei       = (const int2*)d_in[1];
    const float* ew       = (const float*)d_in[2];
    const float* W_in     = (const float*)d_in[3];
    const float* b_in     = (const float*)d_in[4];
    const float* W_layers = (const float*)d_in[5];
    const float* b_layers = (const float*)d_in[6];
    const float* W_out    = (const float*)d_in[7];
    const float* b_out    = (const float*)d_in[8];

    float* out1 = (float*)d_out;
    float* hf32 = out1 + (size_t)N_NODES * OUT_F;  // fp32 h output (written by last layer)

    // workspace layout (~31.5 MB); 16B alignment maintained
    char* ws = (char*)d_ws;
    __half*   h16A  = (__half*)ws;    ws += (size_t)N_NODES * INT_F * 2;        // 12.8 MB
    __half*   h16B  = (__half*)ws;    ws += (size_t)N_NODES * INT_F * 2;        // 12.8 MB
    _Float16* WT16  = (_Float16*)ws;  ws += (size_t)DEPTH * INT_F * INT_F * 2;  // 128 KB
    unsigned int* csru = (unsigned int*)ws;  ws += (size_t)N_EDGES * 4;         // 2.5 MB
    int*  slot    = (int*)ws;   ws += (size_t)N_EDGES * 4;                      // 2.5 MB
    int*  row_ptr = (int*)ws;   ws += (size_t)(N_NODES + 1) * 4;
    int*  deg     = (int*)ws;   ws += (size_t)N_NODES * 4;
    int*  partial = (int*)ws;   ws += (size_t)SCAN_BLOCKS * 4;
    int*  bbase   = (int*)ws;   ws += (size_t)SCAN_BLOCKS * 4;

    // ---- build CSR + transpose weights (once per call) ----
    (void)hipMemsetAsync(deg, 0, (size_t)N_NODES * 4, stream);
    deg_slot_kernel<<<(N_EDGES + 255) / 256, 256, 0, stream>>>(ei, deg, slot);
    scan1_kernel<<<SCAN_BLOCKS, 256, 0, stream>>>(deg, partial);
    scan2_kernel<<<1, 256, 0, stream>>>(partial, bbase, row_ptr);
    scan3_kernel<<<SCAN_BLOCKS, 256, 0, stream>>>(deg, bbase, row_ptr);
    build_csr_kernel<<<(N_EDGES + 255) / 256, 256, 0, stream>>>(ei, ew, slot, row_ptr, csru);
    prep_wt_kernel<<<(DEPTH * INT_F * INT_F) / 256, 256, 0, stream>>>(W_layers, WT16);

    // ---- input projection (fp16 h) ----
    gemm_in_kernel<<<N_NODES / 16, 256, 0, stream>>>(X, W_in, b_in, h16A);

    // ---- fused layers: ping-pong h16A <-> h16B; last layer also writes fp32 h ----
    __half* hin = h16A;
    __half* hout = h16B;
    for (int i = 0; i < DEPTH; ++i) {
        fused_layer_kernel<<<N_NODES / 16, 256, 0, stream>>>(
            row_ptr, csru, hin, WT16 + (size_t)i * INT_F * INT_F,
            b_layers + (size_t)i * INT_F, hout,
            (i == DEPTH - 1) ? hf32 : nullptr);
        __half* tmp = hin; hin = hout; hout = tmp;
    }

    // ---- output projection (hin == final h16 == h16A) ----
    gemm_out_kernel<<<N_NODES / 8, 256, 0, stream>>>(hin, W_out, b_out, out1);
}